// Round 4
// baseline (13463.824 us; speedup 1.0000x reference)
//
#include <hip/hip_runtime.h>
#include <cstdint>

typedef unsigned short u16;
typedef unsigned int u32;
typedef unsigned char u8;

#define CAP 131072  // max compact slots at 128^3 (~105k expected active)

__device__ __forceinline__ float bf1(u16 v){ union{u32 i; float f;} c; c.i = ((u32)v) << 16; return c.f; }
__device__ __forceinline__ u16 f2bf(float f){
    union{float f; u32 i;} c; c.f = f; u32 i = c.i;
    return (u16)((i + 0x7FFFu + ((i >> 16) & 1u)) >> 16);   // RTNE
}
__device__ __forceinline__ float dot4(float4 a, float4 b){ return a.x*b.x + a.y*b.y + a.z*b.z + a.w*b.w; }

constexpr int ilog2c(int n){ return n <= 1 ? 0 : 1 + ilog2c(n / 2); }

// ---- dtype sniff on s0a ~ U(0.5,1.5): bf16 -> every u16 in [0x3F00,0x3FC0];
//      f32 -> even u16 indices are random mantissa halves. ----
__global__ void detect_k(const u16* __restrict__ s0a, u32* __restrict__ flag, u32* __restrict__ cnt){
    if (threadIdx.x == 0){
        int ok = 1;
        #pragma unroll
        for (int i = 0; i < 8; i += 2){
            u16 v = s0a[i];
            if (v < 0x3F00u || v > 0x3FC0u) ok = 0;
        }
        flag[0] = ok ? 1u : 0u;   // 1 = bf16 inputs, 0 = f32 inputs
        cnt[0] = 0;
    }
}

// ---- build idxmap + active list from x (active iff any of 16 ch nonzero) ----
__global__ __launch_bounds__(256)
void build_k(const void* __restrict__ xv, int* __restrict__ idxmap,
             int* __restrict__ alist, u32* __restrict__ cnt,
             const u32* __restrict__ flag){
    const int v = blockIdx.x * 256 + threadIdx.x;
    const size_t N = 2097152;  // 128^3
    u32 a = 0;
    if (flag[0]) {
        const u16* x = (const u16*)xv;
        #pragma unroll
        for (int c = 0; c < 16; ++c) a |= (u32)(x[(size_t)c * N + v]) & 0x7FFFu;
    } else {
        const u32* x = (const u32*)xv;  // f32 bits
        #pragma unroll
        for (int c = 0; c < 16; ++c) a |= x[(size_t)c * N + v] & 0x7FFFFFFFu;
    }
    int slot = -1;
    if (a) {
        slot = (int)atomicAdd(cnt, 1u);
        if (slot < CAP) alist[slot] = v; else slot = -1;
    }
    idxmap[v] = slot;
}

// ---- gather x (NCDHW) into compact f32 F [slot][16] ----
__global__ __launch_bounds__(256)
void gather_k(const void* __restrict__ xv, const int* __restrict__ alist,
              const u32* __restrict__ cnt, float* __restrict__ f,
              const u32* __restrict__ flag){
    const int t = threadIdx.x;
    const int s = blockIdx.x * 16 + (t >> 4);
    const int c = t & 15;
    const int n = min((int)cnt[0], CAP);
    if (s >= n) return;
    const int v = alist[s];
    float val;
    if (flag[0]) val = bf1(((const u16*)xv)[(size_t)c * 2097152 + v]);
    else         val = ((const float*)xv)[(size_t)c * 2097152 + v];
    f[(size_t)s * 16 + c] = val;
}

// ---- m1: 64^3 site active iff any idxmap>=0 in 3^3 stride-2 window ----
__global__ __launch_bounds__(256)
void m1_k(const int* __restrict__ idx, u8* __restrict__ mo){
    const int v = blockIdx.x * 256 + threadIdx.x;
    const int xo = v & 63, yo = (v >> 6) & 63, zo = v >> 12;
    u8 a = 0;
    for (int kz = 0; kz < 3; ++kz){ int iz = 2*zo + kz - 1; if ((unsigned)iz >= 128u) continue;
      for (int ky = 0; ky < 3; ++ky){ int iy = 2*yo + ky - 1; if ((unsigned)iy >= 128u) continue;
        for (int kx = 0; kx < 3; ++kx){ int ix = 2*xo + kx - 1; if ((unsigned)ix >= 128u) continue;
          a |= (idx[((size_t)iz * 128 + iy) * 128 + ix] >= 0) ? 1 : 0;
    }}}
    mo[v] = a;
}

template<int DO>
__global__ __launch_bounds__(256)
void maskdown_k(const u8* __restrict__ mi, u8* __restrict__ mo){
    constexpr int DI = DO * 2;
    constexpr int LOG = ilog2c(DO);
    const int v = blockIdx.x * 256 + threadIdx.x;
    const int xo = v & (DO - 1), yo = (v >> LOG) & (DO - 1), zo = v >> (2 * LOG);
    u8 a = 0;
    for (int kz = 0; kz < 3; ++kz){ int iz = 2*zo + kz - 1; if ((unsigned)iz >= (unsigned)DI) continue;
      for (int ky = 0; ky < 3; ++ky){ int iy = 2*yo + ky - 1; if ((unsigned)iy >= (unsigned)DI) continue;
        for (int kx = 0; kx < 3; ++kx){ int ix = 2*xo + kx - 1; if ((unsigned)ix >= (unsigned)DI) continue;
          a |= mi[((size_t)iz * DI + iy) * DI + ix];
    }}}
    mo[v] = a;
}

// ---- weight transpose+canonicalize: [3,3,3,CIN,COUT] (bf16 or f32) -> f32 [tap][COUT][CIN] ----
__global__ __launch_bounds__(256)
void wtr_k(const void* __restrict__ w, float* __restrict__ wt, int CIN, int COUT,
           const u32* __restrict__ flag){
    const int n = 27 * CIN * COUT;
    const int i = blockIdx.x * 256 + threadIdx.x;
    if (i >= n) return;
    const int cc = CIN * COUT;
    const int tap = i / cc; const int r = i - tap * cc;
    const int ci = r / COUT; const int co = r - ci * COUT;
    const float v = flag[0] ? bf1(((const u16*)w)[i]) : ((const float*)w)[i];
    wt[((size_t)tap * COUT + co) * CIN + ci] = v;
}

// ---- canonicalize the 18 scale/shift vectors into S (f32) ----
struct P18 { const void* p[18]; };
__global__ __launch_bounds__(64)
void scales_k(P18 ps, float* __restrict__ S, const u32* __restrict__ flag){
    const int b = blockIdx.x, t = threadIdx.x;
    const int len[18] = {16,16,16,16,32,32,32,32,32,32,64,64,64,64,64,64,64,64};
    const int off[18] = {0,16,32,48,64,96,128,160,192,224,256,320,384,448,512,576,640,704};
    if (t < len[b]){
        const float v = flag[0] ? bf1(((const u16*)ps.p[b])[t]) : ((const float*)ps.p[b])[t];
        S[off[b] + t] = v;
    }
}

// ---- sparse subm conv at 128^3: compact f32, 16ch -> 16ch ----
__global__ __launch_bounds__(256)
void sconv_k(const float* __restrict__ fin, const int* __restrict__ idxmap,
             const int* __restrict__ alist, const u32* __restrict__ cnt,
             const float* __restrict__ wt, const float* __restrict__ sc,
             const float* __restrict__ sh, float* __restrict__ fout){
    const int t = threadIdx.x;
    const int s = blockIdx.x * 16 + (t >> 4);
    const int co = t & 15;
    const int n = min((int)cnt[0], CAP);
    if (s >= n) return;
    const int v = alist[s];
    const int xo = v & 127, yo = (v >> 7) & 127, zo = v >> 14;
    float acc = 0.f;
    for (int kz = 0; kz < 3; ++kz){ const int iz = zo + kz - 1; if ((unsigned)iz >= 128u) continue;
      for (int ky = 0; ky < 3; ++ky){ const int iy = yo + ky - 1; if ((unsigned)iy >= 128u) continue;
        for (int kx = 0; kx < 3; ++kx){ const int ix = xo + kx - 1; if ((unsigned)ix >= 128u) continue;
          const int sn = idxmap[((size_t)iz * 128 + iy) * 128 + ix];
          if (sn < 0) continue;
          const int tap = (kz * 3 + ky) * 3 + kx;
          const float4* ip = (const float4*)(fin + (size_t)sn * 16);
          const float4* wp = (const float4*)(wt + ((size_t)tap * 16 + co) * 16);
          acc += dot4(ip[0], wp[0]) + dot4(ip[1], wp[1]) + dot4(ip[2], wp[2]) + dot4(ip[3], wp[3]);
    }}}
    fout[(size_t)s * 16 + co] = fmaxf(acc * sc[co] + sh[co], 0.f);
}

// ---- down0: stride-2, compact 16ch @128^3 -> dense NDHWC f32 32ch @64^3 ----
__global__ __launch_bounds__(256)
void convd0_k(const float* __restrict__ fin, const int* __restrict__ idxmap,
              const u8* __restrict__ m1, const float* __restrict__ wt,
              const float* __restrict__ sc, const float* __restrict__ sh,
              float* __restrict__ out){
    const int t = threadIdx.x;
    const int vi = blockIdx.x * 8 + (t >> 5);
    const int co = t & 31;
    if (!m1[vi]) { out[(size_t)vi * 32 + co] = 0.f; return; }
    const int xo = vi & 63, yo = (vi >> 6) & 63, zo = vi >> 12;
    float acc = 0.f;
    for (int kz = 0; kz < 3; ++kz){ const int iz = 2*zo + kz - 1; if ((unsigned)iz >= 128u) continue;
      for (int ky = 0; ky < 3; ++ky){ const int iy = 2*yo + ky - 1; if ((unsigned)iy >= 128u) continue;
        for (int kx = 0; kx < 3; ++kx){ const int ix = 2*xo + kx - 1; if ((unsigned)ix >= 128u) continue;
          const int sn = idxmap[((size_t)iz * 128 + iy) * 128 + ix];
          if (sn < 0) continue;
          const int tap = (kz * 3 + ky) * 3 + kx;
          const float4* ip = (const float4*)(fin + (size_t)sn * 16);
          const float4* wp = (const float4*)(wt + ((size_t)tap * 32 + co) * 16);
          acc += dot4(ip[0], wp[0]) + dot4(ip[1], wp[1]) + dot4(ip[2], wp[2]) + dot4(ip[3], wp[3]);
    }}}
    out[(size_t)vi * 32 + co] = fmaxf(acc * sc[co] + sh[co], 0.f);
}

// ---- dense direct conv (3x3x3, pad 1), NDHWC f32 in, bn+relu fused ----
// OUT_CM: final conv, writes NCDHW to d_out; dtype picked by flag (f32 or bf16).
template<int DIN, int DOUT, int CIN, int COUT, int STRIDE, bool OUT_CM>
__global__ __launch_bounds__(256)
void conv_k(const float* __restrict__ in, const float* __restrict__ wt,
            const float* __restrict__ sc, const float* __restrict__ sh,
            const u8* __restrict__ mk, void* __restrict__ out,
            const u32* __restrict__ flag)
{
    constexpr int VPB = 256 / COUT;
    constexpr int LOG = ilog2c(DOUT);
    constexpr int CLOG = ilog2c(COUT);
    const int t = threadIdx.x;
    const int vi = blockIdx.x * VPB + (t >> CLOG);
    const int co = t & (COUT - 1);
    const int NOUT = DOUT * DOUT * DOUT;
    const size_t oidx = OUT_CM ? ((size_t)co * NOUT + vi) : ((size_t)vi * COUT + co);

    float r = 0.f;
    if (mk[vi]) {
        const int xo = vi & (DOUT - 1), yo = (vi >> LOG) & (DOUT - 1), zo = vi >> (2 * LOG);
        float acc = 0.f;
        for (int kz = 0; kz < 3; ++kz){ const int iz = zo * STRIDE + kz - 1; if ((unsigned)iz >= (unsigned)DIN) continue;
          for (int ky = 0; ky < 3; ++ky){ const int iy = yo * STRIDE + ky - 1; if ((unsigned)iy >= (unsigned)DIN) continue;
            for (int kx = 0; kx < 3; ++kx){ const int ix = xo * STRIDE + kx - 1; if ((unsigned)ix >= (unsigned)DIN) continue;
              const int tap = (kz * 3 + ky) * 3 + kx;
              const size_t nb = ((size_t)iz * DIN + iy) * DIN + ix;
              const float4* ip = (const float4*)(in + nb * CIN);
              const float4* wp = (const float4*)(wt + ((size_t)tap * COUT + co) * CIN);
              #pragma unroll
              for (int k = 0; k < CIN / 4; ++k)
                  acc += dot4(ip[k], wp[k]);
        }}}
        r = fmaxf(acc * sc[co] + sh[co], 0.f);
    }

    if (OUT_CM) {
        if (flag[0]) ((u16*)out)[oidx] = f2bf(r);
        else         ((float*)out)[oidx] = r;
    } else {
        ((float*)out)[oidx] = r;
    }
}

extern "C" void kernel_launch(void* const* d_in, const int* in_sizes, int n_in,
                              void* d_out, int out_size, void* d_ws, size_t ws_size,
                              hipStream_t stream)
{
    (void)out_size; (void)ws_size;

    // Locate w0a by its unambiguous element count (27*16*16 = 6912); robust to
    // mask present/absent. Fallback: assume x, mask, then weights.
    int wb = 2;
    for (int i = 1; i < n_in; ++i) { if (in_sizes[i] == 6912) { wb = i; break; } }

    const void* x = d_in[0];
    const void *w0a=d_in[wb+0],  *s0a=d_in[wb+1],  *b0a=d_in[wb+2];
    const void *w0b=d_in[wb+3],  *s0b=d_in[wb+4],  *b0b=d_in[wb+5];
    const void *wd0=d_in[wb+6],  *sd0=d_in[wb+7],  *bd0=d_in[wb+8];
    const void *w1a=d_in[wb+9],  *s1a=d_in[wb+10], *b1a=d_in[wb+11];
    const void *w1b=d_in[wb+12], *s1b=d_in[wb+13], *b1b=d_in[wb+14];
    const void *wd1=d_in[wb+15], *sd1=d_in[wb+16], *bd1=d_in[wb+17];
    const void *w2a=d_in[wb+18], *s2a=d_in[wb+19], *b2a=d_in[wb+20];
    const void *w2b=d_in[wb+21], *s2b=d_in[wb+22], *b2b=d_in[wb+23];
    const void *w2c=d_in[wb+24], *s2c=d_in[wb+25], *b2c=d_in[wb+26];

    // ---- workspace layout (f32 pipeline, ~90.6 MiB total) ----
    char* ws = (char*)d_ws;
    int*   idxmap = (int*)(ws);                     //  8,388,608
    float* F1     = (float*)(ws + 8388608);         //  8,388,608  (CAP x 16 f32)
    float* F2     = (float*)(ws + 16777216);        //  8,388,608
    float* R1     = (float*)(ws + 25165824);        // 33,554,432  (64^3 x 32 f32)
    float* R2     = (float*)(ws + 58720256);        // 33,554,432
    u8*    m1     = (u8*)(ws + 92274688);           //    262,144
    u8*    m2     = (u8*)(ws + 92536832);           //     32,768
    u32*   cnt    = (u32*)(ws + 92569600);          //        256
    int*   alist  = (int*)(ws + 92569856);          //    524,288
    float* W      = (float*)(ws + 93094144);        //  1,880,064  (470,016 f32)
    float* S      = (float*)(ws + 94974208);        //      3,072  (768 f32)
    u32*   flag   = (u32*)(ws + 94977280);          //          4
    float* t0a = W;
    float* t0b = t0a + 27*16*16;
    float* td0 = t0b + 27*16*16;
    float* t1a = td0 + 27*16*32;
    float* t1b = t1a + 27*32*32;
    float* td1 = t1b + 27*32*32;
    float* t2a = td1 + 27*32*64;
    float* t2b = t2a + 27*64*64;
    float* t2c = t2b + 27*64*64;

    detect_k<<<1, 64, 0, stream>>>((const u16*)s0a, flag, cnt);

    auto tr = [&](const void* src, float* dst, int ci, int co){
        const int n = 27 * ci * co;
        wtr_k<<<(n + 255) / 256, 256, 0, stream>>>(src, dst, ci, co, flag);
    };
    tr(w0a, t0a, 16, 16); tr(w0b, t0b, 16, 16); tr(wd0, td0, 16, 32);
    tr(w1a, t1a, 32, 32); tr(w1b, t1b, 32, 32); tr(wd1, td1, 32, 64);
    tr(w2a, t2a, 64, 64); tr(w2b, t2b, 64, 64); tr(w2c, t2c, 64, 64);

    P18 ps;
    const void* sv[18] = {s0a,b0a,s0b,b0b,sd0,bd0,s1a,b1a,s1b,b1b,sd1,bd1,s2a,b2a,s2b,b2b,s2c,b2c};
    for (int i = 0; i < 18; ++i) ps.p[i] = sv[i];
    scales_k<<<18, 64, 0, stream>>>(ps, S, flag);
    float *cs0a=S+0,  *cb0a=S+16,  *cs0b=S+32,  *cb0b=S+48;
    float *csd0=S+64, *cbd0=S+96,  *cs1a=S+128, *cb1a=S+160, *cs1b=S+192, *cb1b=S+224;
    float *csd1=S+256,*cbd1=S+320, *cs2a=S+384, *cb2a=S+448, *cs2b=S+512, *cb2b=S+576, *cs2c=S+640, *cb2c=S+704;

    build_k<<<8192, 256, 0, stream>>>(x, idxmap, alist, cnt, flag);
    m1_k<<<1024, 256, 0, stream>>>(idxmap, m1);
    maskdown_k<32><<<128, 256, 0, stream>>>(m1, m2);

    // stage A (128^3, 16ch, ~5% active) — compact sparse
    gather_k<<<8192, 256, 0, stream>>>(x, alist, cnt, F2, flag);
    sconv_k<<<8192, 256, 0, stream>>>(F2, idxmap, alist, cnt, t0a, cs0a, cb0a, F1);
    sconv_k<<<8192, 256, 0, stream>>>(F1, idxmap, alist, cnt, t0b, cs0b, cb0b, F2);
    // down0 -> dense 64^3 x 32ch NDHWC f32
    convd0_k<<<32768, 256, 0, stream>>>(F2, idxmap, m1, td0, csd0, cbd0, R1);
    // 64^3 stage
    conv_k<64,64,32,32,1,false><<<32768, 256, 0, stream>>>(R1, t1a, cs1a, cb1a, m1, R2, flag);
    conv_k<64,64,32,32,1,false><<<32768, 256, 0, stream>>>(R2, t1b, cs1b, cb1b, m1, R1, flag);
    // down1 -> 32^3 x 64ch
    conv_k<64,32,32,64,2,false><<< 8192, 256, 0, stream>>>(R1, td1, csd1, cbd1, m2, R2, flag);
    // 32^3 stage
    conv_k<32,32,64,64,1,false><<< 8192, 256, 0, stream>>>(R2, t2a, cs2a, cb2a, m2, R1, flag);
    conv_k<32,32,64,64,1,false><<< 8192, 256, 0, stream>>>(R1, t2b, cs2b, cb2b, m2, R2, flag);
    // final conv writes NCDHW (f32, or bf16 if flag says bf16) to d_out
    conv_k<32,32,64,64,1,true ><<< 8192, 256, 0, stream>>>(R2, t2c, cs2c, cb2c, m2, d_out, flag);
}

// Round 5
// 989.666 us; speedup vs baseline: 13.6044x; 13.6044x over previous
//
#include <hip/hip_runtime.h>
#include <cstdint>

typedef unsigned short u16;
typedef unsigned int u32;
typedef unsigned char u8;
typedef __attribute__((ext_vector_type(8))) short short8;
typedef __attribute__((ext_vector_type(4))) float f32x4;

#define CAP 131072  // max compact slots at 128^3 (~105k expected active)

__device__ __forceinline__ float bf1(u16 v){ union{u32 i; float f;} c; c.i = ((u32)v) << 16; return c.f; }
__device__ __forceinline__ u16 f2bf(float f){
    union{float f; u32 i;} c; c.f = f; u32 i = c.i;
    return (u16)((i + 0x7FFFu + ((i >> 16) & 1u)) >> 16);   // RTNE
}
__device__ __forceinline__ float dot4(float4 a, float4 b){ return a.x*b.x + a.y*b.y + a.z*b.z + a.w*b.w; }

constexpr int ilog2c(int n){ return n <= 1 ? 0 : 1 + ilog2c(n / 2); }

struct P18 { const void* p[18]; };

// ---- dtype sniff on s0a ~ U(0.5,1.5) (flag=0 -> f32, confirmed in R4) ----
__global__ void detect_k(const u16* __restrict__ s0a, u32* __restrict__ flag, u32* __restrict__ cnt){
    if (threadIdx.x == 0){
        int ok = 1;
        #pragma unroll
        for (int i = 0; i < 8; i += 2){
            u16 v = s0a[i];
            if (v < 0x3F00u || v > 0x3FC0u) ok = 0;
        }
        flag[0] = ok ? 1u : 0u;
        cnt[0] = 0;
    }
}

__global__ __launch_bounds__(256)
void build_k(const void* __restrict__ xv, int* __restrict__ idxmap,
             int* __restrict__ alist, u32* __restrict__ cnt,
             const u32* __restrict__ flag){
    const int v = blockIdx.x * 256 + threadIdx.x;
    const size_t N = 2097152;
    u32 a = 0;
    if (flag[0]) {
        const u16* x = (const u16*)xv;
        #pragma unroll
        for (int c = 0; c < 16; ++c) a |= (u32)(x[(size_t)c * N + v]) & 0x7FFFu;
    } else {
        const u32* x = (const u32*)xv;
        #pragma unroll
        for (int c = 0; c < 16; ++c) a |= x[(size_t)c * N + v] & 0x7FFFFFFFu;
    }
    int slot = -1;
    if (a) {
        slot = (int)atomicAdd(cnt, 1u);
        if (slot < CAP) alist[slot] = v; else slot = -1;
    }
    idxmap[v] = slot;
}

__global__ __launch_bounds__(256)
void gather_k(const void* __restrict__ xv, const int* __restrict__ alist,
              const u32* __restrict__ cnt, float* __restrict__ f,
              const u32* __restrict__ flag){
    const int t = threadIdx.x;
    const int s = blockIdx.x * 16 + (t >> 4);
    const int c = t & 15;
    const int n = min((int)cnt[0], CAP);
    if (s >= n) return;
    const int v = alist[s];
    float val;
    if (flag[0]) val = bf1(((const u16*)xv)[(size_t)c * 2097152 + v]);
    else         val = ((const float*)xv)[(size_t)c * 2097152 + v];
    f[(size_t)s * 16 + c] = val;
}

__global__ __launch_bounds__(256)
void m1_k(const int* __restrict__ idx, u8* __restrict__ mo){
    const int v = blockIdx.x * 256 + threadIdx.x;
    const int xo = v & 63, yo = (v >> 6) & 63, zo = v >> 12;
    u8 a = 0;
    for (int kz = 0; kz < 3; ++kz){ int iz = 2*zo + kz - 1; if ((unsigned)iz >= 128u) continue;
      for (int ky = 0; ky < 3; ++ky){ int iy = 2*yo + ky - 1; if ((unsigned)iy >= 128u) continue;
        for (int kx = 0; kx < 3; ++kx){ int ix = 2*xo + kx - 1; if ((unsigned)ix >= 128u) continue;
          a |= (idx[((size_t)iz * 128 + iy) * 128 + ix] >= 0) ? 1 : 0;
    }}}
    mo[v] = a;
}

template<int DO>
__global__ __launch_bounds__(256)
void maskdown_k(const u8* __restrict__ mi, u8* __restrict__ mo){
    constexpr int DI = DO * 2;
    constexpr int LOG = ilog2c(DO);
    const int v = blockIdx.x * 256 + threadIdx.x;
    const int xo = v & (DO - 1), yo = (v >> LOG) & (DO - 1), zo = v >> (2 * LOG);
    u8 a = 0;
    for (int kz = 0; kz < 3; ++kz){ int iz = 2*zo + kz - 1; if ((unsigned)iz >= (unsigned)DI) continue;
      for (int ky = 0; ky < 3; ++ky){ int iy = 2*yo + ky - 1; if ((unsigned)iy >= (unsigned)DI) continue;
        for (int kx = 0; kx < 3; ++kx){ int ix = 2*xo + kx - 1; if ((unsigned)ix >= (unsigned)DI) continue;
          a |= mi[((size_t)iz * DI + iy) * DI + ix];
    }}}
    mo[v] = a;
}

__global__ __launch_bounds__(256)
void wtr_k(const void* __restrict__ w, float* __restrict__ wt, int CIN, int COUT,
           const u32* __restrict__ flag){
    const int n = 27 * CIN * COUT;
    const int i = blockIdx.x * 256 + threadIdx.x;
    if (i >= n) return;
    const int cc = CIN * COUT;
    const int tap = i / cc; const int r = i - tap * cc;
    const int ci = r / COUT; const int co = r - ci * COUT;
    const float v = flag[0] ? bf1(((const u16*)w)[i]) : ((const float*)w)[i];
    wt[((size_t)tap * COUT + co) * CIN + ci] = v;
}

// ---- MFMA B-fragment builder: frag[tap][kc][nt][lane][8] bf16; B[k][n]: n=lane&15, k=kc*32+(lane>>4)*8+j ----
__global__ __launch_bounds__(256)
void wfrag_k(const void* __restrict__ w, u16* __restrict__ wf, int CIN, int COUT,
             const u32* __restrict__ flag){
    const int KC = CIN >> 5, NT = COUT >> 4;
    const int nel = 27 * KC * NT * 512;
    const int i = blockIdx.x * 256 + threadIdx.x;
    if (i >= nel) return;
    const int j = i & 7;
    const int lane = (i >> 3) & 63;
    int rest = i >> 9;
    const int nt = rest % NT; rest /= NT;
    const int kc = rest % KC; const int tap = rest / KC;
    const int k = kc * 32 + (lane >> 4) * 8 + j;
    const int co = nt * 16 + (lane & 15);
    const int src = (tap * CIN + k) * COUT + co;
    const float v = flag[0] ? bf1(((const u16*)w)[src]) : ((const float*)w)[src];
    wf[i] = f2bf(v);
}

// ---- tap-paired fragment builder for down0 (CIN=16 -> 2 taps per K=32) ----
__global__ __launch_bounds__(256)
void wfragd0_k(const void* __restrict__ w, u16* __restrict__ wf,
               const u32* __restrict__ flag){
    const int nel = 14 * 2 * 512;
    const int i = blockIdx.x * 256 + threadIdx.x;
    if (i >= nel) return;
    const int j = i & 7;
    const int lane = (i >> 3) & 63;
    int rest = i >> 9;
    const int nt = rest & 1; const int pair = rest >> 1;
    const int kg = (lane >> 4) * 8 + j;
    const int tap = pair * 2 + (kg >> 4);
    const int ci = kg & 15;
    const int co = nt * 16 + (lane & 15);
    float v = 0.f;
    if (tap < 27) {
        const int src = (tap * 16 + ci) * 32 + co;
        v = flag[0] ? bf1(((const u16*)w)[src]) : ((const float*)w)[src];
    }
    wf[i] = f2bf(v);
}

__global__ __launch_bounds__(64)
void scales_k(P18 ps, float* __restrict__ S, const u32* __restrict__ flag){
    const int b = blockIdx.x, t = threadIdx.x;
    const int len[18] = {16,16,16,16,32,32,32,32,32,32,64,64,64,64,64,64,64,64};
    const int off[18] = {0,16,32,48,64,96,128,160,192,224,256,320,384,448,512,576,640,704};
    if (t < len[b]){
        const float v = flag[0] ? bf1(((const u16*)ps.p[b])[t]) : ((const float*)ps.p[b])[t];
        S[off[b] + t] = v;
    }
}

// ---- sparse subm conv at 128^3 (f32) ----
__global__ __launch_bounds__(256)
void sconv_k(const float* __restrict__ fin, const int* __restrict__ idxmap,
             const int* __restrict__ alist, const u32* __restrict__ cnt,
             const float* __restrict__ wt, const float* __restrict__ sc,
             const float* __restrict__ sh, float* __restrict__ fout){
    const int t = threadIdx.x;
    const int s = blockIdx.x * 16 + (t >> 4);
    const int co = t & 15;
    const int n = min((int)cnt[0], CAP);
    if (s >= n) return;
    const int v = alist[s];
    const int xo = v & 127, yo = (v >> 7) & 127, zo = v >> 14;
    float acc = 0.f;
    for (int kz = 0; kz < 3; ++kz){ const int iz = zo + kz - 1; if ((unsigned)iz >= 128u) continue;
      for (int ky = 0; ky < 3; ++ky){ const int iy = yo + ky - 1; if ((unsigned)iy >= 128u) continue;
        for (int kx = 0; kx < 3; ++kx){ const int ix = xo + kx - 1; if ((unsigned)ix >= 128u) continue;
          const int sn = idxmap[((size_t)iz * 128 + iy) * 128 + ix];
          if (sn < 0) continue;
          const int tap = (kz * 3 + ky) * 3 + kx;
          const float4* ip = (const float4*)(fin + (size_t)sn * 16);
          const float4* wp = (const float4*)(wt + ((size_t)tap * 16 + co) * 16);
          acc += dot4(ip[0], wp[0]) + dot4(ip[1], wp[1]) + dot4(ip[2], wp[2]) + dot4(ip[3], wp[3]);
    }}}
    fout[(size_t)s * 16 + co] = fmaxf(acc * sc[co] + sh[co], 0.f);
}

__global__ __launch_bounds__(256)
void fb_k(const float* __restrict__ f, u16* __restrict__ fb){
    const int i = blockIdx.x * 256 + threadIdx.x;
    fb[i] = f2bf(f[i]);
}

// ---- down0 MFMA: compact bf16 16ch @128^3 (idxmap gather) -> bf16 NDHWC 32ch @64^3 ----
__global__ __launch_bounds__(256)
void convd0m_k(const u16* __restrict__ fbuf, const int* __restrict__ idxmap,
               const u16* __restrict__ wf, const float* __restrict__ sc,
               const float* __restrict__ sh, const u8* __restrict__ mk,
               u16* __restrict__ out)
{
    const int wj = blockIdx.x * 4 + (threadIdx.x >> 6);
    const int lane = threadIdx.x & 63;
    const int m = lane & 15, quad = lane >> 4;
    const int xo_b = (wj & 3) * 16;
    const int yo = (wj >> 2) & 63;
    const int zo = wj >> 8;

    f32x4 acc0 = {0.f,0.f,0.f,0.f}, acc1 = {0.f,0.f,0.f,0.f};
    const int ix_m = (xo_b + m) * 2 - 1;

    for (int p = 0; p < 14; ++p){
        const int tp = p * 2 + (quad >> 1);
        short8 a = {0,0,0,0,0,0,0,0};
        if (tp < 27){
            const int kz = tp / 9, ky = (tp / 3) % 3, kx = tp % 3;
            const int iz = 2*zo + kz - 1, iy = 2*yo + ky - 1, ix = ix_m + kx;
            if ((unsigned)iz < 128u && (unsigned)iy < 128u && (unsigned)ix < 128u){
                const int sn = idxmap[((size_t)iz * 128 + iy) * 128 + ix];
                if (sn >= 0) a = *(const short8*)(fbuf + (size_t)sn * 16 + (quad & 1) * 8);
            }
        }
        short8 b0 = *(const short8*)(wf + ((size_t)(p*2+0) * 64 + lane) * 8);
        short8 b1 = *(const short8*)(wf + ((size_t)(p*2+1) * 64 + lane) * 8);
        acc0 = __builtin_amdgcn_mfma_f32_16x16x32_bf16(a, b0, acc0, 0, 0, 0);
        acc1 = __builtin_amdgcn_mfma_f32_16x16x32_bf16(a, b1, acc1, 0, 0, 0);
    }

    const int vb = wj * 16 + quad * 4;
    const u32 m4 = *(const u32*)(mk + vb);
    const int n = lane & 15;
    #pragma unroll
    for (int nt = 0; nt < 2; ++nt){
        const int co = nt * 16 + n;
        const float s = sc[co], h = sh[co];
        const f32x4 acc = nt ? acc1 : acc0;
        #pragma unroll
        for (int r = 0; r < 4; ++r){
            float val = fmaxf(acc[r] * s + h, 0.f);
            val = ((m4 >> (8*r)) & 0xFFu) ? val : 0.f;
            out[(size_t)(vb + r) * 32 + co] = f2bf(val);
        }
    }
}

// ---- dense MFMA conv (3x3x3, pad 1), bf16 NDHWC in; FINAL writes NCDHW f32 (or bf16 per flag) ----
template<int DIN, int DOUT, int CIN, int COUT, int STRIDE, bool FINAL>
__global__ __launch_bounds__(256)
void mconv_k(const u16* __restrict__ in, const u16* __restrict__ wf,
             const float* __restrict__ sc, const float* __restrict__ sh,
             const u8* __restrict__ mk, void* __restrict__ out,
             const u32* __restrict__ flag)
{
    constexpr int KC = CIN / 32;
    constexpr int NT = COUT / 16;
    constexpr int XT = DOUT / 16;
    const int wj = blockIdx.x * 4 + (threadIdx.x >> 6);
    const int lane = threadIdx.x & 63;
    const int m = lane & 15, quad = lane >> 4;

    const int xo_b = (wj % XT) * 16;
    const int yo = (wj / XT) % DOUT;
    const int zo = wj / (XT * DOUT);

    f32x4 acc[NT];
    #pragma unroll
    for (int i = 0; i < NT; ++i) acc[i] = (f32x4){0.f,0.f,0.f,0.f};

    const int ix0 = (xo_b + m) * STRIDE - 1;
    for (int kz = 0; kz < 3; ++kz){
      const int iz = zo * STRIDE + kz - 1;
      if ((unsigned)iz >= (unsigned)DIN) continue;
      for (int ky = 0; ky < 3; ++ky){
        const int iy = yo * STRIDE + ky - 1;
        if ((unsigned)iy >= (unsigned)DIN) continue;
        const size_t rowb = ((size_t)iz * DIN + iy) * DIN;
        #pragma unroll
        for (int kx = 0; kx < 3; ++kx){
          const int ix = ix0 + kx;
          const bool v = (unsigned)ix < (unsigned)DIN;
          const int tap = (kz*3 + ky)*3 + kx;
          const u16* ap = in + (rowb + ix) * CIN + quad * 8;
          const u16* bp = wf + (size_t)tap * KC * NT * 512 + lane * 8;
          #pragma unroll
          for (int kc = 0; kc < KC; ++kc){
            short8 a = {0,0,0,0,0,0,0,0};
            if (v) a = *(const short8*)(ap + kc * 32);
            #pragma unroll
            for (int nt = 0; nt < NT; ++nt){
              short8 b = *(const short8*)(bp + (kc * NT + nt) * 512);
              acc[nt] = __builtin_amdgcn_mfma_f32_16x16x32_bf16(a, b, acc[nt], 0, 0, 0);
            }
          }
    }}}

    const int vb = wj * 16 + quad * 4;
    const u32 m4 = *(const u32*)(mk + vb);
    const int n = lane & 15;
    if (FINAL) {
        const bool bfout = flag[0] != 0;
        #pragma unroll
        for (int nt = 0; nt < NT; ++nt){
            const int co = nt * 16 + n;
            const float s = sc[co], h = sh[co];
            float4 o;
            float* po = &o.x;
            #pragma unroll
            for (int r = 0; r < 4; ++r){
                float val = fmaxf(acc[nt][r] * s + h, 0.f);
                po[r] = ((m4 >> (8*r)) & 0xFFu) ? val : 0.f;
            }
            if (!bfout) {
                *(float4*)((float*)out + (size_t)co * (DOUT*DOUT*DOUT) + vb) = o;
            } else {
                u16* ob = (u16*)out + (size_t)co * (DOUT*DOUT*DOUT) + vb;
                #pragma unroll
                for (int r = 0; r < 4; ++r) ob[r] = f2bf(po[r]);
            }
        }
    } else {
        #pragma unroll
        for (int nt = 0; nt < NT; ++nt){
            const int co = nt * 16 + n;
            const float s = sc[co], h = sh[co];
            #pragma unroll
            for (int r = 0; r < 4; ++r){
                float val = fmaxf(acc[nt][r] * s + h, 0.f);
                val = ((m4 >> (8*r)) & 0xFFu) ? val : 0.f;
                ((u16*)out)[(size_t)(vb + r) * COUT + co] = f2bf(val);
            }
        }
    }
}

extern "C" void kernel_launch(void* const* d_in, const int* in_sizes, int n_in,
                              void* d_out, int out_size, void* d_ws, size_t ws_size,
                              hipStream_t stream)
{
    (void)out_size; (void)ws_size;

    int wb = 2;
    for (int i = 1; i < n_in; ++i) { if (in_sizes[i] == 6912) { wb = i; break; } }

    const void* x = d_in[0];
    const void *w0a=d_in[wb+0],  *s0a=d_in[wb+1],  *b0a=d_in[wb+2];
    const void *w0b=d_in[wb+3],  *s0b=d_in[wb+4],  *b0b=d_in[wb+5];
    const void *wd0=d_in[wb+6],  *sd0=d_in[wb+7],  *bd0=d_in[wb+8];
    const void *w1a=d_in[wb+9],  *s1a=d_in[wb+10], *b1a=d_in[wb+11];
    const void *w1b=d_in[wb+12], *s1b=d_in[wb+13], *b1b=d_in[wb+14];
    const void *wd1=d_in[wb+15], *sd1=d_in[wb+16], *bd1=d_in[wb+17];
    const void *w2a=d_in[wb+18], *s2a=d_in[wb+19], *b2a=d_in[wb+20];
    const void *w2b=d_in[wb+21], *s2b=d_in[wb+22], *b2b=d_in[wb+23];
    const void *w2c=d_in[wb+24], *s2c=d_in[wb+25], *b2c=d_in[wb+26];

    // ---- workspace layout (~61 MiB) ----
    char* ws = (char*)d_ws;
    int*   idxmap = (int*)(ws);                     //  8,388,608
    float* F1     = (float*)(ws + 8388608);         //  8,388,608
    u16*   Fb     = (u16*)(ws + 8388608);           //  (aliases F1; used after F1 dead)
    float* F2     = (float*)(ws + 16777216);        //  8,388,608
    u16*   Rb1    = (u16*)(ws + 25165824);          // 16,777,216
    u16*   Rb2    = (u16*)(ws + 41943040);          // 16,777,216
    u8*    m1     = (u8*)(ws + 58720256);           //    262,144
    u8*    m2     = (u8*)(ws + 58982400);           //     32,768
    u32*   cnt    = (u32*)(ws + 59015168);          //        256
    int*   alist  = (int*)(ws + 59015424);          //    524,288
    float* Wf     = (float*)(ws + 59539712);        //    131,072 (t0a,t0b f32)
    float* S      = (float*)(ws + 59670784);        //      3,072
    u32*   flag   = (u32*)(ws + 59673856);          //         64
    u16*   WF     = (u16*)(ws + 59673920);          //    913,408
    float* t0a = Wf;
    float* t0b = Wf + 6912;
    u16* f1a = WF;
    u16* f1b = WF + 27648;
    u16* fd1 = WF + 55296;
    u16* f2a = WF + 110592;
    u16* f2b = WF + 221184;
    u16* f2c = WF + 331776;
    u16* fd0 = WF + 442368;

    detect_k<<<1, 64, 0, stream>>>((const u16*)s0a, flag, cnt);

    wtr_k<<<27, 256, 0, stream>>>(w0a, t0a, 16, 16, flag);
    wtr_k<<<27, 256, 0, stream>>>(w0b, t0b, 16, 16, flag);
    wfrag_k<<<108, 256, 0, stream>>>(w1a, f1a, 32, 32, flag);
    wfrag_k<<<108, 256, 0, stream>>>(w1b, f1b, 32, 32, flag);
    wfrag_k<<<216, 256, 0, stream>>>(wd1, fd1, 32, 64, flag);
    wfrag_k<<<432, 256, 0, stream>>>(w2a, f2a, 64, 64, flag);
    wfrag_k<<<432, 256, 0, stream>>>(w2b, f2b, 64, 64, flag);
    wfrag_k<<<432, 256, 0, stream>>>(w2c, f2c, 64, 64, flag);
    wfragd0_k<<<56, 256, 0, stream>>>(wd0, fd0, flag);

    P18 ps;
    const void* sv[18] = {s0a,b0a,s0b,b0b,sd0,bd0,s1a,b1a,s1b,b1b,sd1,bd1,s2a,b2a,s2b,b2b,s2c,b2c};
    for (int i = 0; i < 18; ++i) ps.p[i] = sv[i];
    scales_k<<<18, 64, 0, stream>>>(ps, S, flag);
    float *cs0a=S+0,  *cb0a=S+16,  *cs0b=S+32,  *cb0b=S+48;
    float *csd0=S+64, *cbd0=S+96,  *cs1a=S+128, *cb1a=S+160, *cs1b=S+192, *cb1b=S+224;
    float *csd1=S+256,*cbd1=S+320, *cs2a=S+384, *cb2a=S+448, *cs2b=S+512, *cb2b=S+576, *cs2c=S+640, *cb2c=S+704;

    build_k<<<8192, 256, 0, stream>>>(x, idxmap, alist, cnt, flag);
    m1_k<<<1024, 256, 0, stream>>>(idxmap, m1);
    maskdown_k<32><<<128, 256, 0, stream>>>(m1, m2);

    // stage A (128^3, 16ch, ~5% active) — compact sparse f32
    gather_k<<<8192, 256, 0, stream>>>(x, alist, cnt, F2, flag);
    sconv_k<<<8192, 256, 0, stream>>>(F2, idxmap, alist, cnt, t0a, cs0a, cb0a, F1);
    sconv_k<<<8192, 256, 0, stream>>>(F1, idxmap, alist, cnt, t0b, cs0b, cb0b, F2);
    fb_k<<<8192, 256, 0, stream>>>(F2, Fb);   // F1 dead -> Fb aliases it safely
    // down0 MFMA -> 64^3 x 32 bf16 NDHWC
    convd0m_k<<<4096, 256, 0, stream>>>(Fb, idxmap, fd0, csd0, cbd0, m1, Rb1);
    // 64^3 stage
    mconv_k<64,64,32,32,1,false><<<4096, 256, 0, stream>>>(Rb1, f1a, cs1a, cb1a, m1, Rb2, flag);
    mconv_k<64,64,32,32,1,false><<<4096, 256, 0, stream>>>(Rb2, f1b, cs1b, cb1b, m1, Rb1, flag);
    // down1 -> 32^3 x 64
    mconv_k<64,32,32,64,2,false><<<512, 256, 0, stream>>>(Rb1, fd1, csd1, cbd1, m2, Rb2, flag);
    // 32^3 stage
    mconv_k<32,32,64,64,1,false><<<512, 256, 0, stream>>>(Rb2, f2a, cs2a, cb2a, m2, Rb1, flag);
    mconv_k<32,32,64,64,1,false><<<512, 256, 0, stream>>>(Rb1, f2b, cs2b, cb2b, m2, Rb2, flag);
    // final conv: NCDHW f32 (or bf16 per flag) to d_out
    mconv_k<32,32,64,64,1,true ><<<512, 256, 0, stream>>>(Rb2, f2c, cs2c, cb2c, m2, d_out, flag);
}

// Round 6
// 682.332 us; speedup vs baseline: 19.7321x; 1.4504x over previous
//
#include <hip/hip_runtime.h>
#include <cstdint>

typedef unsigned short u16;
typedef unsigned int u32;
typedef unsigned char u8;
typedef unsigned long long u64;
typedef __attribute__((ext_vector_type(8))) short short8;
typedef __attribute__((ext_vector_type(4))) float f32x4;

#define CAP 131072  // max compact slots at 128^3 (~105k expected active)

__device__ __forceinline__ float bf1(u16 v){ union{u32 i; float f;} c; c.i = ((u32)v) << 16; return c.f; }
__device__ __forceinline__ u16 f2bf(float f){
    union{float f; u32 i;} c; c.f = f; u32 i = c.i;
    return (u16)((i + 0x7FFFu + ((i >> 16) & 1u)) >> 16);   // RTNE
}
__device__ __forceinline__ float dot4(float4 a, float4 b){ return a.x*b.x + a.y*b.y + a.z*b.z + a.w*b.w; }

constexpr int ilog2c(int n){ return n <= 1 ? 0 : 1 + ilog2c(n / 2); }

struct P18 { const void* p[18]; };

// ---- dtype sniff on s0a ~ U(0.5,1.5) (flag=0 -> f32, confirmed in R4) ----
__global__ void detect_k(const u16* __restrict__ s0a, u32* __restrict__ flag){
    if (threadIdx.x == 0){
        int ok = 1;
        #pragma unroll
        for (int i = 0; i < 8; i += 2){
            u16 v = s0a[i];
            if (v < 0x3F00u || v > 0x3FC0u) ok = 0;
        }
        flag[0] = ok ? 1u : 0u;
    }
}

// ---- phase 1: active bitmask (per-wave ballot) + per-block counts, atomic-free ----
__global__ __launch_bounds__(256)
void actmask_k(const void* __restrict__ xv, u64* __restrict__ bmask,
               u32* __restrict__ bcnt, const u32* __restrict__ flag){
    const int v = blockIdx.x * 256 + threadIdx.x;
    const size_t N = 2097152;
    u32 a = 0;
    if (flag[0]) {
        const u16* x = (const u16*)xv;
        #pragma unroll
        for (int c = 0; c < 16; ++c) a |= (u32)(x[(size_t)c * N + v]) & 0x7FFFu;
    } else {
        const u32* x = (const u32*)xv;
        #pragma unroll
        for (int c = 0; c < 16; ++c) a |= x[(size_t)c * N + v] & 0x7FFFFFFFu;
    }
    const u64 m = __ballot(a != 0);
    __shared__ u32 wc[4];
    const int lane = threadIdx.x & 63, wv = threadIdx.x >> 6;
    if (lane == 0) { bmask[v >> 6] = m; wc[wv] = (u32)__popcll(m); }
    __syncthreads();
    if (threadIdx.x == 0) bcnt[blockIdx.x] = wc[0] + wc[1] + wc[2] + wc[3];
}

// ---- phase 2: exclusive scan of 8192 block counts (single block) ----
__global__ __launch_bounds__(1024)
void scan_k(const u32* __restrict__ bcnt, u32* __restrict__ boff, u32* __restrict__ cnt){
    __shared__ u32 lds[1024];
    const int t = threadIdx.x;
    u32 loc[8]; u32 s = 0;
    #pragma unroll
    for (int i = 0; i < 8; ++i){ loc[i] = s; s += bcnt[t * 8 + i]; }
    lds[t] = s;
    __syncthreads();
    u32 v = s;
    for (int d = 1; d < 1024; d <<= 1){
        u32 o = (t >= d) ? lds[t - d] : 0;
        __syncthreads();
        v += o; lds[t] = v;
        __syncthreads();
    }
    const u32 base = v - s;  // exclusive base for this thread's chunk
    #pragma unroll
    for (int i = 0; i < 8; ++i) boff[t * 8 + i] = base + loc[i];
    if (t == 1023) cnt[0] = v;
}

// ---- phase 3: deterministic scatter (slot = blockOff + waveBase + rank) ----
__global__ __launch_bounds__(256)
void scatter_k(const u64* __restrict__ bmask, const u32* __restrict__ boff,
               int* __restrict__ idxmap, int* __restrict__ alist){
    const int v = blockIdx.x * 256 + threadIdx.x;
    const int lane = threadIdx.x & 63, wv = threadIdx.x >> 6;
    const u64 m = bmask[v >> 6];
    __shared__ u32 wc[4];
    if (lane == 0) wc[wv] = (u32)__popcll(m);
    __syncthreads();
    u32 wbase = 0;
    for (int i = 0; i < wv; ++i) wbase += wc[i];
    const bool act = (m >> lane) & 1ull;
    const u32 rank = (u32)__popcll(m & ((1ull << lane) - 1ull));
    int slot = -1;
    if (act){
        const u32 sl = boff[blockIdx.x] + wbase + rank;
        if (sl < CAP){ slot = (int)sl; alist[slot] = v; }
    }
    idxmap[v] = slot;
}

__global__ __launch_bounds__(256)
void gather_k(const void* __restrict__ xv, const int* __restrict__ alist,
              const u32* __restrict__ cnt, float* __restrict__ f,
              const u32* __restrict__ flag){
    const int t = threadIdx.x;
    const int s = blockIdx.x * 16 + (t >> 4);
    const int c = t & 15;
    const int n = min((int)cnt[0], CAP);
    if (s >= n) return;
    const int v = alist[s];
    float val;
    if (flag[0]) val = bf1(((const u16*)xv)[(size_t)c * 2097152 + v]);
    else         val = ((const float*)xv)[(size_t)c * 2097152 + v];
    f[(size_t)s * 16 + c] = val;
}

__global__ __launch_bounds__(256)
void m1_k(const int* __restrict__ idx, u8* __restrict__ mo){
    const int v = blockIdx.x * 256 + threadIdx.x;
    const int xo = v & 63, yo = (v >> 6) & 63, zo = v >> 12;
    u8 a = 0;
    for (int kz = 0; kz < 3; ++kz){ int iz = 2*zo + kz - 1; if ((unsigned)iz >= 128u) continue;
      for (int ky = 0; ky < 3; ++ky){ int iy = 2*yo + ky - 1; if ((unsigned)iy >= 128u) continue;
        for (int kx = 0; kx < 3; ++kx){ int ix = 2*xo + kx - 1; if ((unsigned)ix >= 128u) continue;
          a |= (idx[((size_t)iz * 128 + iy) * 128 + ix] >= 0) ? 1 : 0;
    }}}
    mo[v] = a;
}

template<int DO>
__global__ __launch_bounds__(256)
void maskdown_k(const u8* __restrict__ mi, u8* __restrict__ mo){
    constexpr int DI = DO * 2;
    constexpr int LOG = ilog2c(DO);
    const int v = blockIdx.x * 256 + threadIdx.x;
    const int xo = v & (DO - 1), yo = (v >> LOG) & (DO - 1), zo = v >> (2 * LOG);
    u8 a = 0;
    for (int kz = 0; kz < 3; ++kz){ int iz = 2*zo + kz - 1; if ((unsigned)iz >= (unsigned)DI) continue;
      for (int ky = 0; ky < 3; ++ky){ int iy = 2*yo + ky - 1; if ((unsigned)iy >= (unsigned)DI) continue;
        for (int kx = 0; kx < 3; ++kx){ int ix = 2*xo + kx - 1; if ((unsigned)ix >= (unsigned)DI) continue;
          a |= mi[((size_t)iz * DI + iy) * DI + ix];
    }}}
    mo[v] = a;
}

__global__ __launch_bounds__(256)
void wtr_k(const void* __restrict__ w, float* __restrict__ wt, int CIN, int COUT,
           const u32* __restrict__ flag){
    const int n = 27 * CIN * COUT;
    const int i = blockIdx.x * 256 + threadIdx.x;
    if (i >= n) return;
    const int cc = CIN * COUT;
    const int tap = i / cc; const int r = i - tap * cc;
    const int ci = r / COUT; const int co = r - ci * COUT;
    const float v = flag[0] ? bf1(((const u16*)w)[i]) : ((const float*)w)[i];
    wt[((size_t)tap * COUT + co) * CIN + ci] = v;
}

// ---- MFMA B-fragment builder: frag[tap][kc][nt][lane][8] bf16 ----
__global__ __launch_bounds__(256)
void wfrag_k(const void* __restrict__ w, u16* __restrict__ wf, int CIN, int COUT,
             const u32* __restrict__ flag){
    const int KC = CIN >> 5, NT = COUT >> 4;
    const int nel = 27 * KC * NT * 512;
    const int i = blockIdx.x * 256 + threadIdx.x;
    if (i >= nel) return;
    const int j = i & 7;
    const int lane = (i >> 3) & 63;
    int rest = i >> 9;
    const int nt = rest % NT; rest /= NT;
    const int kc = rest % KC; const int tap = rest / KC;
    const int k = kc * 32 + (lane >> 4) * 8 + j;
    const int co = nt * 16 + (lane & 15);
    const int src = (tap * CIN + k) * COUT + co;
    const float v = flag[0] ? bf1(((const u16*)w)[src]) : ((const float*)w)[src];
    wf[i] = f2bf(v);
}

// ---- tap-paired fragment builder for down0 (CIN=16 -> 2 taps per K=32) ----
__global__ __launch_bounds__(256)
void wfragd0_k(const void* __restrict__ w, u16* __restrict__ wf,
               const u32* __restrict__ flag){
    const int nel = 14 * 2 * 512;
    const int i = blockIdx.x * 256 + threadIdx.x;
    if (i >= nel) return;
    const int j = i & 7;
    const int lane = (i >> 3) & 63;
    int rest = i >> 9;
    const int nt = rest & 1; const int pair = rest >> 1;
    const int kg = (lane >> 4) * 8 + j;
    const int tap = pair * 2 + (kg >> 4);
    const int ci = kg & 15;
    const int co = nt * 16 + (lane & 15);
    float v = 0.f;
    if (tap < 27) {
        const int src = (tap * 16 + ci) * 32 + co;
        v = flag[0] ? bf1(((const u16*)w)[src]) : ((const float*)w)[src];
    }
    wf[i] = f2bf(v);
}

__global__ __launch_bounds__(64)
void scales_k(P18 ps, float* __restrict__ S, const u32* __restrict__ flag){
    const int b = blockIdx.x, t = threadIdx.x;
    const int len[18] = {16,16,16,16,32,32,32,32,32,32,64,64,64,64,64,64,64,64};
    const int off[18] = {0,16,32,48,64,96,128,160,192,224,256,320,384,448,512,576,640,704};
    if (t < len[b]){
        const float v = flag[0] ? bf1(((const u16*)ps.p[b])[t]) : ((const float*)ps.p[b])[t];
        S[off[b] + t] = v;
    }
}

// ---- sparse subm conv at 128^3 (f32) ----
__global__ __launch_bounds__(256)
void sconv_k(const float* __restrict__ fin, const int* __restrict__ idxmap,
             const int* __restrict__ alist, const u32* __restrict__ cnt,
             const float* __restrict__ wt, const float* __restrict__ sc,
             const float* __restrict__ sh, float* __restrict__ fout){
    const int t = threadIdx.x;
    const int s = blockIdx.x * 16 + (t >> 4);
    const int co = t & 15;
    const int n = min((int)cnt[0], CAP);
    if (s >= n) return;
    const int v = alist[s];
    const int xo = v & 127, yo = (v >> 7) & 127, zo = v >> 14;
    float acc = 0.f;
    for (int kz = 0; kz < 3; ++kz){ const int iz = zo + kz - 1; if ((unsigned)iz >= 128u) continue;
      for (int ky = 0; ky < 3; ++ky){ const int iy = yo + ky - 1; if ((unsigned)iy >= 128u) continue;
        for (int kx = 0; kx < 3; ++kx){ const int ix = xo + kx - 1; if ((unsigned)ix >= 128u) continue;
          const int sn = idxmap[((size_t)iz * 128 + iy) * 128 + ix];
          if (sn < 0) continue;
          const int tap = (kz * 3 + ky) * 3 + kx;
          const float4* ip = (const float4*)(fin + (size_t)sn * 16);
          const float4* wp = (const float4*)(wt + ((size_t)tap * 16 + co) * 16);
          acc += dot4(ip[0], wp[0]) + dot4(ip[1], wp[1]) + dot4(ip[2], wp[2]) + dot4(ip[3], wp[3]);
    }}}
    fout[(size_t)s * 16 + co] = fmaxf(acc * sc[co] + sh[co], 0.f);
}

__global__ __launch_bounds__(256)
void fb_k(const float* __restrict__ f, u16* __restrict__ fb){
    const int i = blockIdx.x * 256 + threadIdx.x;
    fb[i] = f2bf(f[i]);
}

// ---- down0 MFMA: compact bf16 16ch @128^3 (idxmap gather) -> bf16 NDHWC 32ch @64^3 ----
__global__ __launch_bounds__(256)
void convd0m_k(const u16* __restrict__ fbuf, const int* __restrict__ idxmap,
               const u16* __restrict__ wf, const float* __restrict__ sc,
               const float* __restrict__ sh, const u8* __restrict__ mk,
               u16* __restrict__ out)
{
    const int wj = blockIdx.x * 4 + (threadIdx.x >> 6);
    const int lane = threadIdx.x & 63;
    const int m = lane & 15, quad = lane >> 4;
    const int xo_b = (wj & 3) * 16;
    const int yo = (wj >> 2) & 63;
    const int zo = wj >> 8;

    f32x4 acc0 = {0.f,0.f,0.f,0.f}, acc1 = {0.f,0.f,0.f,0.f};
    const int ix_m = (xo_b + m) * 2 - 1;

    for (int p = 0; p < 14; ++p){
        const int tp = p * 2 + (quad >> 1);
        short8 a = {0,0,0,0,0,0,0,0};
        if (tp < 27){
            const int kz = tp / 9, ky = (tp / 3) % 3, kx = tp % 3;
            const int iz = 2*zo + kz - 1, iy = 2*yo + ky - 1, ix = ix_m + kx;
            if ((unsigned)iz < 128u && (unsigned)iy < 128u && (unsigned)ix < 128u){
                const int sn = idxmap[((size_t)iz * 128 + iy) * 128 + ix];
                if (sn >= 0) a = *(const short8*)(fbuf + (size_t)sn * 16 + (quad & 1) * 8);
            }
        }
        short8 b0 = *(const short8*)(wf + ((size_t)(p*2+0) * 64 + lane) * 8);
        short8 b1 = *(const short8*)(wf + ((size_t)(p*2+1) * 64 + lane) * 8);
        acc0 = __builtin_amdgcn_mfma_f32_16x16x32_bf16(a, b0, acc0, 0, 0, 0);
        acc1 = __builtin_amdgcn_mfma_f32_16x16x32_bf16(a, b1, acc1, 0, 0, 0);
    }

    const int vb = wj * 16 + quad * 4;
    const u32 m4 = *(const u32*)(mk + vb);
    const int n = lane & 15;
    #pragma unroll
    for (int nt = 0; nt < 2; ++nt){
        const int co = nt * 16 + n;
        const float s = sc[co], h = sh[co];
        const f32x4 acc = nt ? acc1 : acc0;
        #pragma unroll
        for (int r = 0; r < 4; ++r){
            float val = fmaxf(acc[r] * s + h, 0.f);
            val = ((m4 >> (8*r)) & 0xFFu) ? val : 0.f;
            out[(size_t)(vb + r) * 32 + co] = f2bf(val);
        }
    }
}

// ---- dense MFMA conv (3x3x3, pad 1), bf16 NDHWC in; FINAL writes NCDHW f32 (or bf16 per flag) ----
template<int DIN, int DOUT, int CIN, int COUT, int STRIDE, bool FINAL>
__global__ __launch_bounds__(256)
void mconv_k(const u16* __restrict__ in, const u16* __restrict__ wf,
             const float* __restrict__ sc, const float* __restrict__ sh,
             const u8* __restrict__ mk, void* __restrict__ out,
             const u32* __restrict__ flag)
{
    constexpr int KC = CIN / 32;
    constexpr int NT = COUT / 16;
    constexpr int XT = DOUT / 16;
    const int wj = blockIdx.x * 4 + (threadIdx.x >> 6);
    const int lane = threadIdx.x & 63;
    const int m = lane & 15, quad = lane >> 4;

    const int xo_b = (wj % XT) * 16;
    const int yo = (wj / XT) % DOUT;
    const int zo = wj / (XT * DOUT);

    f32x4 acc[NT];
    #pragma unroll
    for (int i = 0; i < NT; ++i) acc[i] = (f32x4){0.f,0.f,0.f,0.f};

    const int ix0 = (xo_b + m) * STRIDE - 1;
    for (int kz = 0; kz < 3; ++kz){
      const int iz = zo * STRIDE + kz - 1;
      if ((unsigned)iz >= (unsigned)DIN) continue;
      for (int ky = 0; ky < 3; ++ky){
        const int iy = yo * STRIDE + ky - 1;
        if ((unsigned)iy >= (unsigned)DIN) continue;
        const size_t rowb = ((size_t)iz * DIN + iy) * DIN;
        #pragma unroll
        for (int kx = 0; kx < 3; ++kx){
          const int ix = ix0 + kx;
          const bool v = (unsigned)ix < (unsigned)DIN;
          const int tap = (kz*3 + ky)*3 + kx;
          const u16* ap = in + (rowb + ix) * CIN + quad * 8;
          const u16* bp = wf + (size_t)tap * KC * NT * 512 + lane * 8;
          #pragma unroll
          for (int kc = 0; kc < KC; ++kc){
            short8 a = {0,0,0,0,0,0,0,0};
            if (v) a = *(const short8*)(ap + kc * 32);
            #pragma unroll
            for (int nt = 0; nt < NT; ++nt){
              short8 b = *(const short8*)(bp + (kc * NT + nt) * 512);
              acc[nt] = __builtin_amdgcn_mfma_f32_16x16x32_bf16(a, b, acc[nt], 0, 0, 0);
            }
          }
    }}}

    const int vb = wj * 16 + quad * 4;
    const u32 m4 = *(const u32*)(mk + vb);
    const int n = lane & 15;
    if (FINAL) {
        const bool bfout = flag[0] != 0;
        #pragma unroll
        for (int nt = 0; nt < NT; ++nt){
            const int co = nt * 16 + n;
            const float s = sc[co], h = sh[co];
            float4 o;
            float* po = &o.x;
            #pragma unroll
            for (int r = 0; r < 4; ++r){
                float val = fmaxf(acc[nt][r] * s + h, 0.f);
                po[r] = ((m4 >> (8*r)) & 0xFFu) ? val : 0.f;
            }
            if (!bfout) {
                *(float4*)((float*)out + (size_t)co * (DOUT*DOUT*DOUT) + vb) = o;
            } else {
                u16* ob = (u16*)out + (size_t)co * (DOUT*DOUT*DOUT) + vb;
                #pragma unroll
                for (int r = 0; r < 4; ++r) ob[r] = f2bf(po[r]);
            }
        }
    } else {
        #pragma unroll
        for (int nt = 0; nt < NT; ++nt){
            const int co = nt * 16 + n;
            const float s = sc[co], h = sh[co];
            #pragma unroll
            for (int r = 0; r < 4; ++r){
                float val = fmaxf(acc[nt][r] * s + h, 0.f);
                val = ((m4 >> (8*r)) & 0xFFu) ? val : 0.f;
                ((u16*)out)[(size_t)(vb + r) * COUT + co] = f2bf(val);
            }
        }
    }
}

extern "C" void kernel_launch(void* const* d_in, const int* in_sizes, int n_in,
                              void* d_out, int out_size, void* d_ws, size_t ws_size,
                              hipStream_t stream)
{
    (void)out_size; (void)ws_size;

    int wb = 2;
    for (int i = 1; i < n_in; ++i) { if (in_sizes[i] == 6912) { wb = i; break; } }

    const void* x = d_in[0];
    const void *w0a=d_in[wb+0],  *s0a=d_in[wb+1],  *b0a=d_in[wb+2];
    const void *w0b=d_in[wb+3],  *s0b=d_in[wb+4],  *b0b=d_in[wb+5];
    const void *wd0=d_in[wb+6],  *sd0=d_in[wb+7],  *bd0=d_in[wb+8];
    const void *w1a=d_in[wb+9],  *s1a=d_in[wb+10], *b1a=d_in[wb+11];
    const void *w1b=d_in[wb+12], *s1b=d_in[wb+13], *b1b=d_in[wb+14];
    const void *wd1=d_in[wb+15], *sd1=d_in[wb+16], *bd1=d_in[wb+17];
    const void *w2a=d_in[wb+18], *s2a=d_in[wb+19], *b2a=d_in[wb+20];
    const void *w2b=d_in[wb+21], *s2b=d_in[wb+22], *b2b=d_in[wb+23];
    const void *w2c=d_in[wb+24], *s2c=d_in[wb+25], *b2c=d_in[wb+26];

    // ---- workspace layout (~58.1 MiB) ----
    char* ws = (char*)d_ws;
    int*   idxmap = (int*)(ws);                     //  8,388,608
    float* F1     = (float*)(ws + 8388608);         //  8,388,608
    u16*   Fb     = (u16*)(ws + 8388608);           //  (aliases F1; used after F1 dead)
    float* F2     = (float*)(ws + 16777216);        //  8,388,608
    u16*   Rb1    = (u16*)(ws + 25165824);          // 16,777,216
    u16*   Rb2    = (u16*)(ws + 41943040);          // 16,777,216
    u8*    m1     = (u8*)(ws + 58720256);           //    262,144
    u8*    m2     = (u8*)(ws + 58982400);           //     32,768
    u32*   cnt    = (u32*)(ws + 59015168);          //        256
    int*   alist  = (int*)(ws + 59015424);          //    524,288
    float* Wf     = (float*)(ws + 59539712);        //    131,072 (t0a,t0b f32)
    float* S      = (float*)(ws + 59670784);        //      3,072
    u32*   flag   = (u32*)(ws + 59673856);          //         64
    u16*   WF     = (u16*)(ws + 59673920);          //    913,408
    u64*   bmask  = (u64*)(ws + 60587328);          //    262,144
    u32*   bcnt   = (u32*)(ws + 60849472);          //     32,768
    u32*   boff   = (u32*)(ws + 60882240);          //     32,768
    float* t0a = Wf;
    float* t0b = Wf + 6912;
    u16* f1a = WF;
    u16* f1b = WF + 27648;
    u16* fd1 = WF + 55296;
    u16* f2a = WF + 110592;
    u16* f2b = WF + 221184;
    u16* f2c = WF + 331776;
    u16* fd0 = WF + 442368;

    detect_k<<<1, 64, 0, stream>>>((const u16*)s0a, flag);

    wtr_k<<<27, 256, 0, stream>>>(w0a, t0a, 16, 16, flag);
    wtr_k<<<27, 256, 0, stream>>>(w0b, t0b, 16, 16, flag);
    wfrag_k<<<108, 256, 0, stream>>>(w1a, f1a, 32, 32, flag);
    wfrag_k<<<108, 256, 0, stream>>>(w1b, f1b, 32, 32, flag);
    wfrag_k<<<216, 256, 0, stream>>>(wd1, fd1, 32, 64, flag);
    wfrag_k<<<432, 256, 0, stream>>>(w2a, f2a, 64, 64, flag);
    wfrag_k<<<432, 256, 0, stream>>>(w2b, f2b, 64, 64, flag);
    wfrag_k<<<432, 256, 0, stream>>>(w2c, f2c, 64, 64, flag);
    wfragd0_k<<<56, 256, 0, stream>>>(wd0, fd0, flag);

    P18 ps;
    const void* sv[18] = {s0a,b0a,s0b,b0b,sd0,bd0,s1a,b1a,s1b,b1b,sd1,bd1,s2a,b2a,s2b,b2b,s2c,b2c};
    for (int i = 0; i < 18; ++i) ps.p[i] = sv[i];
    scales_k<<<18, 64, 0, stream>>>(ps, S, flag);
    float *cs0a=S+0,  *cb0a=S+16,  *cs0b=S+32,  *cb0b=S+48;
    float *csd0=S+64, *cbd0=S+96,  *cs1a=S+128, *cb1a=S+160, *cs1b=S+192, *cb1b=S+224;
    float *csd1=S+256,*cbd1=S+320, *cs2a=S+384, *cb2a=S+448, *cs2b=S+512, *cb2b=S+576, *cs2c=S+640, *cb2c=S+704;

    // deterministic compaction (atomic-free)
    actmask_k<<<8192, 256, 0, stream>>>(x, bmask, bcnt, flag);
    scan_k<<<1, 1024, 0, stream>>>(bcnt, boff, cnt);
    scatter_k<<<8192, 256, 0, stream>>>(bmask, boff, idxmap, alist);
    m1_k<<<1024, 256, 0, stream>>>(idxmap, m1);
    maskdown_k<32><<<128, 256, 0, stream>>>(m1, m2);

    // stage A (128^3, 16ch, ~5% active) — compact sparse f32
    gather_k<<<8192, 256, 0, stream>>>(x, alist, cnt, F2, flag);
    sconv_k<<<8192, 256, 0, stream>>>(F2, idxmap, alist, cnt, t0a, cs0a, cb0a, F1);
    sconv_k<<<8192, 256, 0, stream>>>(F1, idxmap, alist, cnt, t0b, cs0b, cb0b, F2);
    fb_k<<<8192, 256, 0, stream>>>(F2, Fb);   // F1 dead -> Fb aliases it safely
    // down0 MFMA -> 64^3 x 32 bf16 NDHWC
    convd0m_k<<<4096, 256, 0, stream>>>(Fb, idxmap, fd0, csd0, cbd0, m1, Rb1);
    // 64^3 stage
    mconv_k<64,64,32,32,1,false><<<4096, 256, 0, stream>>>(Rb1, f1a, cs1a, cb1a, m1, Rb2, flag);
    mconv_k<64,64,32,32,1,false><<<4096, 256, 0, stream>>>(Rb2, f1b, cs1b, cb1b, m1, Rb1, flag);
    // down1 -> 32^3 x 64
    mconv_k<64,32,32,64,2,false><<<512, 256, 0, stream>>>(Rb1, fd1, csd1, cbd1, m2, Rb2, flag);
    // 32^3 stage
    mconv_k<32,32,64,64,1,false><<<512, 256, 0, stream>>>(Rb2, f2a, cs2a, cb2a, m2, Rb1, flag);
    mconv_k<32,32,64,64,1,false><<<512, 256, 0, stream>>>(Rb1, f2b, cs2b, cb2b, m2, Rb2, flag);
    // final conv: NCDHW f32 (or bf16 per flag) to d_out
    mconv_k<32,32,64,64,1,true ><<<512, 256, 0, stream>>>(Rb2, f2c, cs2c, cb2c, m2, d_out, flag);
}

// Round 7
// 584.538 us; speedup vs baseline: 23.0333x; 1.1673x over previous
//
#include <hip/hip_runtime.h>
#include <cstdint>

typedef unsigned short u16;
typedef unsigned int u32;
typedef unsigned char u8;
typedef unsigned long long u64;
typedef __attribute__((ext_vector_type(8))) short short8;
typedef __attribute__((ext_vector_type(4))) float f32x4;

#define CAP 131072  // max compact slots at 128^3 (~105k expected active)

__device__ __forceinline__ float bf1(u16 v){ union{u32 i; float f;} c; c.i = ((u32)v) << 16; return c.f; }
__device__ __forceinline__ u16 f2bf(float f){
    union{float f; u32 i;} c; c.f = f; u32 i = c.i;
    return (u16)((i + 0x7FFFu + ((i >> 16) & 1u)) >> 16);   // RTNE
}

constexpr int ilog2c(int n){ return n <= 1 ? 0 : 1 + ilog2c(n / 2); }

struct P18 { const void* p[18]; };

// ---- dtype sniff on s0a ~ U(0.5,1.5) (flag=0 -> f32, confirmed in R4) ----
__global__ void detect_k(const u16* __restrict__ s0a, u32* __restrict__ flag){
    if (threadIdx.x == 0){
        int ok = 1;
        #pragma unroll
        for (int i = 0; i < 8; i += 2){
            u16 v = s0a[i];
            if (v < 0x3F00u || v > 0x3FC0u) ok = 0;
        }
        flag[0] = ok ? 1u : 0u;
    }
}

// ---- phase 1: active bitmask (per-wave ballot) + per-block counts, atomic-free ----
__global__ __launch_bounds__(256)
void actmask_k(const void* __restrict__ xv, u64* __restrict__ bmask,
               u32* __restrict__ bcnt, const u32* __restrict__ flag){
    const int v = blockIdx.x * 256 + threadIdx.x;
    const size_t N = 2097152;
    u32 a = 0;
    if (flag[0]) {
        const u16* x = (const u16*)xv;
        #pragma unroll
        for (int c = 0; c < 16; ++c) a |= (u32)(x[(size_t)c * N + v]) & 0x7FFFu;
    } else {
        const u32* x = (const u32*)xv;
        #pragma unroll
        for (int c = 0; c < 16; ++c) a |= x[(size_t)c * N + v] & 0x7FFFFFFFu;
    }
    const u64 m = __ballot(a != 0);
    __shared__ u32 wc[4];
    const int lane = threadIdx.x & 63, wv = threadIdx.x >> 6;
    if (lane == 0) { bmask[v >> 6] = m; wc[wv] = (u32)__popcll(m); }
    __syncthreads();
    if (threadIdx.x == 0) bcnt[blockIdx.x] = wc[0] + wc[1] + wc[2] + wc[3];
}

// ---- phase 2: exclusive scan of 8192 block counts (single block) ----
__global__ __launch_bounds__(1024)
void scan_k(const u32* __restrict__ bcnt, u32* __restrict__ boff, u32* __restrict__ cnt){
    __shared__ u32 lds[1024];
    const int t = threadIdx.x;
    u32 loc[8]; u32 s = 0;
    #pragma unroll
    for (int i = 0; i < 8; ++i){ loc[i] = s; s += bcnt[t * 8 + i]; }
    lds[t] = s;
    __syncthreads();
    u32 v = s;
    for (int d = 1; d < 1024; d <<= 1){
        u32 o = (t >= d) ? lds[t - d] : 0;
        __syncthreads();
        v += o; lds[t] = v;
        __syncthreads();
    }
    const u32 base = v - s;
    #pragma unroll
    for (int i = 0; i < 8; ++i) boff[t * 8 + i] = base + loc[i];
    if (t == 1023) cnt[0] = v;
}

// ---- phase 3: deterministic scatter ----
__global__ __launch_bounds__(256)
void scatter_k(const u64* __restrict__ bmask, const u32* __restrict__ boff,
               int* __restrict__ idxmap, int* __restrict__ alist){
    const int v = blockIdx.x * 256 + threadIdx.x;
    const int lane = threadIdx.x & 63, wv = threadIdx.x >> 6;
    const u64 m = bmask[v >> 6];
    __shared__ u32 wc[4];
    if (lane == 0) wc[wv] = (u32)__popcll(m);
    __syncthreads();
    u32 wbase = 0;
    for (int i = 0; i < wv; ++i) wbase += wc[i];
    const bool act = (m >> lane) & 1ull;
    const u32 rank = (u32)__popcll(m & ((1ull << lane) - 1ull));
    int slot = -1;
    if (act){
        const u32 sl = boff[blockIdx.x] + wbase + rank;
        if (sl < CAP){ slot = (int)sl; alist[slot] = v; }
    }
    idxmap[v] = slot;
}

// ---- gather x (NCDHW) into compact bf16 Fb [slot][16] ----
__global__ __launch_bounds__(256)
void gatherb_k(const void* __restrict__ xv, const int* __restrict__ alist,
               const u32* __restrict__ cnt, u16* __restrict__ f,
               const u32* __restrict__ flag){
    const int t = threadIdx.x;
    const int s = blockIdx.x * 16 + (t >> 4);
    const int c = t & 15;
    const int n = min((int)cnt[0], CAP);
    if (s >= n) return;
    const int v = alist[s];
    u16 val;
    if (flag[0]) val = ((const u16*)xv)[(size_t)c * 2097152 + v];
    else         val = f2bf(((const float*)xv)[(size_t)c * 2097152 + v]);
    f[(size_t)s * 16 + c] = val;
}

__global__ __launch_bounds__(256)
void m1_k(const int* __restrict__ idx, u8* __restrict__ mo){
    const int v = blockIdx.x * 256 + threadIdx.x;
    const int xo = v & 63, yo = (v >> 6) & 63, zo = v >> 12;
    u8 a = 0;
    for (int kz = 0; kz < 3; ++kz){ int iz = 2*zo + kz - 1; if ((unsigned)iz >= 128u) continue;
      for (int ky = 0; ky < 3; ++ky){ int iy = 2*yo + ky - 1; if ((unsigned)iy >= 128u) continue;
        for (int kx = 0; kx < 3; ++kx){ int ix = 2*xo + kx - 1; if ((unsigned)ix >= 128u) continue;
          a |= (idx[((size_t)iz * 128 + iy) * 128 + ix] >= 0) ? 1 : 0;
    }}}
    mo[v] = a;
}

template<int DO>
__global__ __launch_bounds__(256)
void maskdown_k(const u8* __restrict__ mi, u8* __restrict__ mo){
    constexpr int DI = DO * 2;
    constexpr int LOG = ilog2c(DO);
    const int v = blockIdx.x * 256 + threadIdx.x;
    const int xo = v & (DO - 1), yo = (v >> LOG) & (DO - 1), zo = v >> (2 * LOG);
    u8 a = 0;
    for (int kz = 0; kz < 3; ++kz){ int iz = 2*zo + kz - 1; if ((unsigned)iz >= (unsigned)DI) continue;
      for (int ky = 0; ky < 3; ++ky){ int iy = 2*yo + ky - 1; if ((unsigned)iy >= (unsigned)DI) continue;
        for (int kx = 0; kx < 3; ++kx){ int ix = 2*xo + kx - 1; if ((unsigned)ix >= (unsigned)DI) continue;
          a |= mi[((size_t)iz * DI + iy) * DI + ix];
    }}}
    mo[v] = a;
}

// ---- MFMA B-fragment builder: frag[tap][kc][nt][lane][8] bf16; B[k][n]: n=lane&15, k=kc*32+(lane>>4)*8+j ----
__global__ __launch_bounds__(256)
void wfrag_k(const void* __restrict__ w, u16* __restrict__ wf, int CIN, int COUT,
             const u32* __restrict__ flag){
    const int KC = CIN >> 5, NT = COUT >> 4;
    const int nel = 27 * KC * NT * 512;
    const int i = blockIdx.x * 256 + threadIdx.x;
    if (i >= nel) return;
    const int j = i & 7;
    const int lane = (i >> 3) & 63;
    int rest = i >> 9;
    const int nt = rest % NT; rest /= NT;
    const int kc = rest % KC; const int tap = rest / KC;
    const int k = kc * 32 + (lane >> 4) * 8 + j;
    const int co = nt * 16 + (lane & 15);
    const int src = (tap * CIN + k) * COUT + co;
    const float v = flag[0] ? bf1(((const u16*)w)[src]) : ((const float*)w)[src];
    wf[i] = f2bf(v);
}

// ---- tap-paired fragment builder, CIN=16 COUT=32 (down0): 2 taps per K=32 ----
__global__ __launch_bounds__(256)
void wfragd0_k(const void* __restrict__ w, u16* __restrict__ wf,
               const u32* __restrict__ flag){
    const int nel = 14 * 2 * 512;
    const int i = blockIdx.x * 256 + threadIdx.x;
    if (i >= nel) return;
    const int j = i & 7;
    const int lane = (i >> 3) & 63;
    int rest = i >> 9;
    const int nt = rest & 1; const int pair = rest >> 1;
    const int kg = (lane >> 4) * 8 + j;
    const int tap = pair * 2 + (kg >> 4);
    const int ci = kg & 15;
    const int co = nt * 16 + (lane & 15);
    float v = 0.f;
    if (tap < 27) {
        const int src = (tap * 16 + ci) * 32 + co;
        v = flag[0] ? bf1(((const u16*)w)[src]) : ((const float*)w)[src];
    }
    wf[i] = f2bf(v);
}

// ---- tap-paired fragment builder, CIN=16 COUT=16 (subm0): frag[pair][lane][8] ----
__global__ __launch_bounds__(256)
void wfrags_k(const void* __restrict__ w, u16* __restrict__ wf,
              const u32* __restrict__ flag){
    const int nel = 14 * 512;
    const int i = blockIdx.x * 256 + threadIdx.x;
    if (i >= nel) return;
    const int j = i & 7;
    const int lane = (i >> 3) & 63;
    const int pair = i >> 9;
    const int kg = (lane >> 4) * 8 + j;
    const int tap = pair * 2 + (kg >> 4);
    const int ci = kg & 15;
    const int co = lane & 15;
    float v = 0.f;
    if (tap < 27) {
        const int src = (tap * 16 + ci) * 16 + co;
        v = flag[0] ? bf1(((const u16*)w)[src]) : ((const float*)w)[src];
    }
    wf[i] = f2bf(v);
}

__global__ __launch_bounds__(64)
void scales_k(P18 ps, float* __restrict__ S, const u32* __restrict__ flag){
    const int b = blockIdx.x, t = threadIdx.x;
    const int len[18] = {16,16,16,16,32,32,32,32,32,32,64,64,64,64,64,64,64,64};
    const int off[18] = {0,16,32,48,64,96,128,160,192,224,256,320,384,448,512,576,640,704};
    if (t < len[b]){
        const float v = flag[0] ? bf1(((const u16*)ps.p[b])[t]) : ((const float*)ps.p[b])[t];
        S[off[b] + t] = v;
    }
}

// ---- MFMA sparse subm conv at 128^3: compact bf16 16ch -> 16ch ----
// wave = 16 compact slots; K=32 packs 2 taps x 16 cin (pairing matches wfrags_k)
__global__ __launch_bounds__(256)
void sconvm_k(const u16* __restrict__ fin, const int* __restrict__ idxmap,
              const int* __restrict__ alist, const u32* __restrict__ cnt,
              const u16* __restrict__ wf, const float* __restrict__ sc,
              const float* __restrict__ sh, u16* __restrict__ fout){
    const int n = min((int)cnt[0], CAP);
    const int j = blockIdx.x * 4 + (threadIdx.x >> 6);
    const int sbase = j * 16;
    if (sbase >= n) return;
    const int lane = threadIdx.x & 63;
    const int m = lane & 15, quad = lane >> 4;

    const int s = sbase + m;
    const int v = (s < n) ? alist[s] : -1;
    int xo = 0, yo = 0, zo = 0;
    if (v >= 0){ xo = v & 127; yo = (v >> 7) & 127; zo = v >> 14; }

    f32x4 acc = {0.f,0.f,0.f,0.f};
    for (int p = 0; p < 14; ++p){
        const int tp = p * 2 + (quad >> 1);
        short8 a = {0,0,0,0,0,0,0,0};
        if (v >= 0 && tp < 27){
            const int kz = tp / 9, ky = (tp / 3) % 3, kx = tp % 3;
            const int iz = zo + kz - 1, iy = yo + ky - 1, ix = xo + kx - 1;
            if ((unsigned)iz < 128u && (unsigned)iy < 128u && (unsigned)ix < 128u){
                const int sn = idxmap[((size_t)iz * 128 + iy) * 128 + ix];
                if (sn >= 0) a = *(const short8*)(fin + (size_t)sn * 16 + (quad & 1) * 8);
            }
        }
        short8 b = *(const short8*)(wf + ((size_t)p * 64 + lane) * 8);
        acc = __builtin_amdgcn_mfma_f32_16x16x32_bf16(a, b, acc, 0, 0, 0);
    }

    const int co = lane & 15;
    const float scl = sc[co], shf = sh[co];
    #pragma unroll
    for (int r = 0; r < 4; ++r){
        const int srow = sbase + quad * 4 + r;
        if (srow < n){
            fout[(size_t)srow * 16 + co] = f2bf(fmaxf(acc[r] * scl + shf, 0.f));
        }
    }
}

// ---- down0 MFMA: compact bf16 16ch @128^3 (idxmap gather) -> bf16 NDHWC 32ch @64^3 ----
__global__ __launch_bounds__(256)
void convd0m_k(const u16* __restrict__ fbuf, const int* __restrict__ idxmap,
               const u16* __restrict__ wf, const float* __restrict__ sc,
               const float* __restrict__ sh, const u8* __restrict__ mk,
               u16* __restrict__ out)
{
    const int wj = blockIdx.x * 4 + (threadIdx.x >> 6);
    const int lane = threadIdx.x & 63;
    const int m = lane & 15, quad = lane >> 4;
    const int xo_b = (wj & 3) * 16;
    const int yo = (wj >> 2) & 63;
    const int zo = wj >> 8;

    f32x4 acc0 = {0.f,0.f,0.f,0.f}, acc1 = {0.f,0.f,0.f,0.f};
    const int ix_m = (xo_b + m) * 2 - 1;

    for (int p = 0; p < 14; ++p){
        const int tp = p * 2 + (quad >> 1);
        short8 a = {0,0,0,0,0,0,0,0};
        if (tp < 27){
            const int kz = tp / 9, ky = (tp / 3) % 3, kx = tp % 3;
            const int iz = 2*zo + kz - 1, iy = 2*yo + ky - 1, ix = ix_m + kx;
            if ((unsigned)iz < 128u && (unsigned)iy < 128u && (unsigned)ix < 128u){
                const int sn = idxmap[((size_t)iz * 128 + iy) * 128 + ix];
                if (sn >= 0) a = *(const short8*)(fbuf + (size_t)sn * 16 + (quad & 1) * 8);
            }
        }
        short8 b0 = *(const short8*)(wf + ((size_t)(p*2+0) * 64 + lane) * 8);
        short8 b1 = *(const short8*)(wf + ((size_t)(p*2+1) * 64 + lane) * 8);
        acc0 = __builtin_amdgcn_mfma_f32_16x16x32_bf16(a, b0, acc0, 0, 0, 0);
        acc1 = __builtin_amdgcn_mfma_f32_16x16x32_bf16(a, b1, acc1, 0, 0, 0);
    }

    const int vb = wj * 16 + quad * 4;
    const u32 m4 = *(const u32*)(mk + vb);
    const int n = lane & 15;
    #pragma unroll
    for (int nt = 0; nt < 2; ++nt){
        const int co = nt * 16 + n;
        const float s = sc[co], h = sh[co];
        const f32x4 acc = nt ? acc1 : acc0;
        #pragma unroll
        for (int r = 0; r < 4; ++r){
            float val = fmaxf(acc[r] * s + h, 0.f);
            val = ((m4 >> (8*r)) & 0xFFu) ? val : 0.f;
            out[(size_t)(vb + r) * 32 + co] = f2bf(val);
        }
    }
}

// ---- dense MFMA conv (3x3x3, pad 1), bf16 NDHWC in; FINAL writes NCDHW f32 (or bf16 per flag) ----
template<int DIN, int DOUT, int CIN, int COUT, int STRIDE, bool FINAL>
__global__ __launch_bounds__(256)
void mconv_k(const u16* __restrict__ in, const u16* __restrict__ wf,
             const float* __restrict__ sc, const float* __restrict__ sh,
             const u8* __restrict__ mk, void* __restrict__ out,
             const u32* __restrict__ flag)
{
    constexpr int KC = CIN / 32;
    constexpr int NT = COUT / 16;
    constexpr int XT = DOUT / 16;
    const int wj = blockIdx.x * 4 + (threadIdx.x >> 6);
    const int lane = threadIdx.x & 63;
    const int m = lane & 15, quad = lane >> 4;

    const int xo_b = (wj % XT) * 16;
    const int yo = (wj / XT) % DOUT;
    const int zo = wj / (XT * DOUT);

    f32x4 acc[NT];
    #pragma unroll
    for (int i = 0; i < NT; ++i) acc[i] = (f32x4){0.f,0.f,0.f,0.f};

    const int ix0 = (xo_b + m) * STRIDE - 1;
    for (int kz = 0; kz < 3; ++kz){
      const int iz = zo * STRIDE + kz - 1;
      if ((unsigned)iz >= (unsigned)DIN) continue;
      for (int ky = 0; ky < 3; ++ky){
        const int iy = yo * STRIDE + ky - 1;
        if ((unsigned)iy >= (unsigned)DIN) continue;
        const size_t rowb = ((size_t)iz * DIN + iy) * DIN;
        #pragma unroll
        for (int kx = 0; kx < 3; ++kx){
          const int ix = ix0 + kx;
          const bool v = (unsigned)ix < (unsigned)DIN;
          const int tap = (kz*3 + ky)*3 + kx;
          const u16* ap = in + (rowb + ix) * CIN + quad * 8;
          const u16* bp = wf + (size_t)tap * KC * NT * 512 + lane * 8;
          #pragma unroll
          for (int kc = 0; kc < KC; ++kc){
            short8 a = {0,0,0,0,0,0,0,0};
            if (v) a = *(const short8*)(ap + kc * 32);
            #pragma unroll
            for (int nt = 0; nt < NT; ++nt){
              short8 b = *(const short8*)(bp + (kc * NT + nt) * 512);
              acc[nt] = __builtin_amdgcn_mfma_f32_16x16x32_bf16(a, b, acc[nt], 0, 0, 0);
            }
          }
    }}}

    const int vb = wj * 16 + quad * 4;
    const u32 m4 = *(const u32*)(mk + vb);
    const int n = lane & 15;
    if (FINAL) {
        const bool bfout = flag[0] != 0;
        #pragma unroll
        for (int nt = 0; nt < NT; ++nt){
            const int co = nt * 16 + n;
            const float s = sc[co], h = sh[co];
            float4 o;
            float* po = &o.x;
            #pragma unroll
            for (int r = 0; r < 4; ++r){
                float val = fmaxf(acc[nt][r] * s + h, 0.f);
                po[r] = ((m4 >> (8*r)) & 0xFFu) ? val : 0.f;
            }
            if (!bfout) {
                *(float4*)((float*)out + (size_t)co * (DOUT*DOUT*DOUT) + vb) = o;
            } else {
                u16* ob = (u16*)out + (size_t)co * (DOUT*DOUT*DOUT) + vb;
                #pragma unroll
                for (int r = 0; r < 4; ++r) ob[r] = f2bf(po[r]);
            }
        }
    } else {
        #pragma unroll
        for (int nt = 0; nt < NT; ++nt){
            const int co = nt * 16 + n;
            const float s = sc[co], h = sh[co];
            #pragma unroll
            for (int r = 0; r < 4; ++r){
                float val = fmaxf(acc[nt][r] * s + h, 0.f);
                val = ((m4 >> (8*r)) & 0xFFu) ? val : 0.f;
                ((u16*)out)[(size_t)(vb + r) * COUT + co] = f2bf(val);
            }
        }
    }
}

extern "C" void kernel_launch(void* const* d_in, const int* in_sizes, int n_in,
                              void* d_out, int out_size, void* d_ws, size_t ws_size,
                              hipStream_t stream)
{
    (void)out_size; (void)ws_size;

    int wb = 2;
    for (int i = 1; i < n_in; ++i) { if (in_sizes[i] == 6912) { wb = i; break; } }

    const void* x = d_in[0];
    const void *w0a=d_in[wb+0],  *s0a=d_in[wb+1],  *b0a=d_in[wb+2];
    const void *w0b=d_in[wb+3],  *s0b=d_in[wb+4],  *b0b=d_in[wb+5];
    const void *wd0=d_in[wb+6],  *sd0=d_in[wb+7],  *bd0=d_in[wb+8];
    const void *w1a=d_in[wb+9],  *s1a=d_in[wb+10], *b1a=d_in[wb+11];
    const void *w1b=d_in[wb+12], *s1b=d_in[wb+13], *b1b=d_in[wb+14];
    const void *wd1=d_in[wb+15], *sd1=d_in[wb+16], *bd1=d_in[wb+17];
    const void *w2a=d_in[wb+18], *s2a=d_in[wb+19], *b2a=d_in[wb+20];
    const void *w2b=d_in[wb+21], *s2b=d_in[wb+22], *b2b=d_in[wb+23];
    const void *w2c=d_in[wb+24], *s2c=d_in[wb+25], *b2c=d_in[wb+26];

    // ---- workspace layout (~58.1 MiB) ----
    char* ws = (char*)d_ws;
    int*   idxmap = (int*)(ws);                     //  8,388,608
    u16*   Fb0    = (u16*)(ws + 8388608);           //  4,194,304 (CAP x 16 bf16)
    u16*   Fb1    = (u16*)(ws + 12582912);          //  4,194,304
    u16*   Fb2    = (u16*)(ws + 16777216);          //  4,194,304
    u16*   Rb1    = (u16*)(ws + 25165824);          // 16,777,216
    u16*   Rb2    = (u16*)(ws + 41943040);          // 16,777,216
    u8*    m1     = (u8*)(ws + 58720256);           //    262,144
    u8*    m2     = (u8*)(ws + 58982400);           //     32,768
    u32*   cnt    = (u32*)(ws + 59015168);          //        256
    int*   alist  = (int*)(ws + 59015424);          //    524,288
    u16*   Ws     = (u16*)(ws + 59539712);          //    131,072 (subm0 fragments)
    float* S      = (float*)(ws + 59670784);        //      3,072
    u32*   flag   = (u32*)(ws + 59673856);          //         64
    u16*   WF     = (u16*)(ws + 59673920);          //    913,408
    u64*   bmask  = (u64*)(ws + 60587328);          //    262,144
    u32*   bcnt   = (u32*)(ws + 60849472);          //     32,768
    u32*   boff   = (u32*)(ws + 60882240);          //     32,768
    u16* wfs0a = Ws;           // 7168 els
    u16* wfs0b = Ws + 7168;    // 7168 els
    u16* f1a = WF;
    u16* f1b = WF + 27648;
    u16* fd1 = WF + 55296;
    u16* f2a = WF + 110592;
    u16* f2b = WF + 221184;
    u16* f2c = WF + 331776;
    u16* fd0 = WF + 442368;

    detect_k<<<1, 64, 0, stream>>>((const u16*)s0a, flag);

    wfrags_k<<<28, 256, 0, stream>>>(w0a, wfs0a, flag);
    wfrags_k<<<28, 256, 0, stream>>>(w0b, wfs0b, flag);
    wfragd0_k<<<56, 256, 0, stream>>>(wd0, fd0, flag);
    wfrag_k<<<108, 256, 0, stream>>>(w1a, f1a, 32, 32, flag);
    wfrag_k<<<108, 256, 0, stream>>>(w1b, f1b, 32, 32, flag);
    wfrag_k<<<216, 256, 0, stream>>>(wd1, fd1, 32, 64, flag);
    wfrag_k<<<432, 256, 0, stream>>>(w2a, f2a, 64, 64, flag);
    wfrag_k<<<432, 256, 0, stream>>>(w2b, f2b, 64, 64, flag);
    wfrag_k<<<432, 256, 0, stream>>>(w2c, f2c, 64, 64, flag);

    P18 ps;
    const void* sv[18] = {s0a,b0a,s0b,b0b,sd0,bd0,s1a,b1a,s1b,b1b,sd1,bd1,s2a,b2a,s2b,b2b,s2c,b2c};
    for (int i = 0; i < 18; ++i) ps.p[i] = sv[i];
    scales_k<<<18, 64, 0, stream>>>(ps, S, flag);
    float *cs0a=S+0,  *cb0a=S+16,  *cs0b=S+32,  *cb0b=S+48;
    float *csd0=S+64, *cbd0=S+96,  *cs1a=S+128, *cb1a=S+160, *cs1b=S+192, *cb1b=S+224;
    float *csd1=S+256,*cbd1=S+320, *cs2a=S+384, *cb2a=S+448, *cs2b=S+512, *cb2b=S+576, *cs2c=S+640, *cb2c=S+704;

    // deterministic compaction (atomic-free)
    actmask_k<<<8192, 256, 0, stream>>>(x, bmask, bcnt, flag);
    scan_k<<<1, 1024, 0, stream>>>(bcnt, boff, cnt);
    scatter_k<<<8192, 256, 0, stream>>>(bmask, boff, idxmap, alist);
    m1_k<<<1024, 256, 0, stream>>>(idxmap, m1);
    maskdown_k<32><<<128, 256, 0, stream>>>(m1, m2);

    // stage A (128^3, 16ch, ~5% active) — compact bf16 MFMA
    gatherb_k<<<8192, 256, 0, stream>>>(x, alist, cnt, Fb0, flag);
    sconvm_k<<<2048, 256, 0, stream>>>(Fb0, idxmap, alist, cnt, wfs0a, cs0a, cb0a, Fb1);
    sconvm_k<<<2048, 256, 0, stream>>>(Fb1, idxmap, alist, cnt, wfs0b, cs0b, cb0b, Fb2);
    // down0 MFMA -> 64^3 x 32 bf16 NDHWC
    convd0m_k<<<4096, 256, 0, stream>>>(Fb2, idxmap, fd0, csd0, cbd0, m1, Rb1);
    // 64^3 stage
    mconv_k<64,64,32,32,1,false><<<4096, 256, 0, stream>>>(Rb1, f1a, cs1a, cb1a, m1, Rb2, flag);
    mconv_k<64,64,32,32,1,false><<<4096, 256, 0, stream>>>(Rb2, f1b, cs1b, cb1b, m1, Rb1, flag);
    // down1 -> 32^3 x 64
    mconv_k<64,32,32,64,2,false><<<512, 256, 0, stream>>>(Rb1, fd1, csd1, cbd1, m2, Rb2, flag);
    // 32^3 stage
    mconv_k<32,32,64,64,1,false><<<512, 256, 0, stream>>>(Rb2, f2a, cs2a, cb2a, m2, Rb1, flag);
    mconv_k<32,32,64,64,1,false><<<512, 256, 0, stream>>>(Rb1, f2b, cs2b, cb2b, m2, Rb2, flag);
    // final conv: NCDHW f32 (or bf16 per flag) to d_out
    mconv_k<32,32,64,64,1,true ><<<512, 256, 0, stream>>>(Rb2, f2c, cs2c, cb2c, m2, d_out, flag);
}

// Round 8
// 542.034 us; speedup vs baseline: 24.8395x; 1.0784x over previous
//
#include <hip/hip_runtime.h>
#include <cstdint>

typedef unsigned short u16;
typedef unsigned int u32;
typedef unsigned char u8;
typedef unsigned long long u64;
typedef __attribute__((ext_vector_type(8))) short short8;
typedef __attribute__((ext_vector_type(4))) float f32x4;

#define CAP 131072  // max compact slots at 128^3 (~105k expected active)

__device__ __forceinline__ float bf1(u16 v){ union{u32 i; float f;} c; c.i = ((u32)v) << 16; return c.f; }
__device__ __forceinline__ u16 f2bf(float f){
    union{float f; u32 i;} c; c.f = f; u32 i = c.i;
    return (u16)((i + 0x7FFFu + ((i >> 16) & 1u)) >> 16);   // RTNE
}

constexpr int ilog2c(int n){ return n <= 1 ? 0 : 1 + ilog2c(n / 2); }

struct P18 { const void* p[18]; };
struct PJobs {
    const void* src[9];
    u32 start[10];
    int cin[9], cout[9], mode[9];   // mode: 0=generic wfrag, 1=d0 pair(16->32), 2=subm0 pair(16->16)
};

// ---- dtype sniff on s0a ~ U(0.5,1.5) (flag=0 -> f32, confirmed in R4) ----
__global__ void detect_k(const u16* __restrict__ s0a, u32* __restrict__ flag){
    if (threadIdx.x == 0){
        int ok = 1;
        #pragma unroll
        for (int i = 0; i < 8; i += 2){
            u16 v = s0a[i];
            if (v < 0x3F00u || v > 0x3FC0u) ok = 0;
        }
        flag[0] = ok ? 1u : 0u;
    }
}

// ---- unified weight-fragment prep (9 jobs in one launch) ----
__global__ __launch_bounds__(256)
void prep_k(PJobs J, u16* __restrict__ FR, const u32* __restrict__ flag){
    const int gi = blockIdx.x * 256 + threadIdx.x;
    if (gi >= (int)J.start[9]) return;
    int j = 0;
    while (gi >= (int)J.start[j + 1]) ++j;
    const int i = gi - (int)J.start[j];
    const void* w = J.src[j];
    const int CIN = J.cin[j], COUT = J.cout[j];
    const int jj = i & 7;
    const int lane = (i >> 3) & 63;
    int rest = i >> 9;
    int src = -1;
    if (J.mode[j] == 0){
        const int KC = CIN >> 5, NT = COUT >> 4;
        const int nt = rest % NT; rest /= NT;
        const int kc = rest % KC; const int tap = rest / KC;
        const int k = kc * 32 + (lane >> 4) * 8 + jj;
        const int co = nt * 16 + (lane & 15);
        src = (tap * CIN + k) * COUT + co;
    } else if (J.mode[j] == 1){
        const int nt = rest & 1; const int pair = rest >> 1;
        const int kg = (lane >> 4) * 8 + jj;
        const int tap = pair * 2 + (kg >> 4);
        const int ci = kg & 15;
        const int co = nt * 16 + (lane & 15);
        if (tap < 27) src = (tap * 16 + ci) * 32 + co;
    } else {
        const int pair = rest;
        const int kg = (lane >> 4) * 8 + jj;
        const int tap = pair * 2 + (kg >> 4);
        const int ci = kg & 15;
        const int co = lane & 15;
        if (tap < 27) src = (tap * 16 + ci) * 16 + co;
    }
    float v = 0.f;
    if (src >= 0) v = flag[0] ? bf1(((const u16*)w)[src]) : ((const float*)w)[src];
    FR[gi] = f2bf(v);
}

__global__ __launch_bounds__(64)
void scales_k(P18 ps, float* __restrict__ S, const u32* __restrict__ flag){
    const int b = blockIdx.x, t = threadIdx.x;
    const int len[18] = {16,16,16,16,32,32,32,32,32,32,64,64,64,64,64,64,64,64};
    const int off[18] = {0,16,32,48,64,96,128,160,192,224,256,320,384,448,512,576,640,704};
    if (t < len[b]){
        const float v = flag[0] ? bf1(((const u16*)ps.p[b])[t]) : ((const float*)ps.p[b])[t];
        S[off[b] + t] = v;
    }
}

// ---- phase 1: active bitmask (per-wave ballot) + per-block counts ----
__global__ __launch_bounds__(256)
void actmask_k(const void* __restrict__ xv, u64* __restrict__ bmask,
               u32* __restrict__ bcnt, const u32* __restrict__ flag){
    const int v = blockIdx.x * 256 + threadIdx.x;
    const size_t N = 2097152;
    u32 a = 0;
    if (flag[0]) {
        const u16* x = (const u16*)xv;
        #pragma unroll
        for (int c = 0; c < 16; ++c) a |= (u32)(x[(size_t)c * N + v]) & 0x7FFFu;
    } else {
        const u32* x = (const u32*)xv;
        #pragma unroll
        for (int c = 0; c < 16; ++c) a |= x[(size_t)c * N + v] & 0x7FFFFFFFu;
    }
    const u64 m = __ballot(a != 0);
    __shared__ u32 wc[4];
    const int lane = threadIdx.x & 63, wv = threadIdx.x >> 6;
    if (lane == 0) { bmask[v >> 6] = m; wc[wv] = (u32)__popcll(m); }
    __syncthreads();
    if (threadIdx.x == 0) bcnt[blockIdx.x] = wc[0] + wc[1] + wc[2] + wc[3];
}

// ---- phase 2: exclusive scan of 8192 block counts (single block) ----
__global__ __launch_bounds__(1024)
void scan_k(const u32* __restrict__ bcnt, u32* __restrict__ boff, u32* __restrict__ cnt){
    __shared__ u32 lds[1024];
    const int t = threadIdx.x;
    u32 loc[8]; u32 s = 0;
    #pragma unroll
    for (int i = 0; i < 8; ++i){ loc[i] = s; s += bcnt[t * 8 + i]; }
    lds[t] = s;
    __syncthreads();
    u32 v = s;
    for (int d = 1; d < 1024; d <<= 1){
        u32 o = (t >= d) ? lds[t - d] : 0;
        __syncthreads();
        v += o; lds[t] = v;
        __syncthreads();
    }
    const u32 base = v - s;
    #pragma unroll
    for (int i = 0; i < 8; ++i) boff[t * 8 + i] = base + loc[i];
    if (t == 1023) cnt[0] = v;
}

// ---- phase 3: deterministic scatter ----
__global__ __launch_bounds__(256)
void scatter_k(const u64* __restrict__ bmask, const u32* __restrict__ boff,
               int* __restrict__ idxmap, int* __restrict__ alist){
    const int v = blockIdx.x * 256 + threadIdx.x;
    const int lane = threadIdx.x & 63, wv = threadIdx.x >> 6;
    const u64 m = bmask[v >> 6];
    __shared__ u32 wc[4];
    if (lane == 0) wc[wv] = (u32)__popcll(m);
    __syncthreads();
    u32 wbase = 0;
    for (int i = 0; i < wv; ++i) wbase += wc[i];
    const bool act = (m >> lane) & 1ull;
    const u32 rank = (u32)__popcll(m & ((1ull << lane) - 1ull));
    int slot = -1;
    if (act){
        const u32 sl = boff[blockIdx.x] + wbase + rank;
        if (sl < CAP){ slot = (int)sl; alist[slot] = v; }
    }
    idxmap[v] = slot;
}

// ---- gather x (NCDHW) into compact bf16 Fb [slot][16] ----
__global__ __launch_bounds__(256)
void gatherb_k(const void* __restrict__ xv, const int* __restrict__ alist,
               const u32* __restrict__ cnt, u16* __restrict__ f,
               const u32* __restrict__ flag){
    const int t = threadIdx.x;
    const int s = blockIdx.x * 16 + (t >> 4);
    const int c = t & 15;
    const int n = min((int)cnt[0], CAP);
    if (s >= n) return;
    const int v = alist[s];
    u16 val;
    if (flag[0]) val = ((const u16*)xv)[(size_t)c * 2097152 + v];
    else         val = f2bf(((const float*)xv)[(size_t)c * 2097152 + v]);
    f[(size_t)s * 16 + c] = val;
}

__global__ __launch_bounds__(256)
void m1_k(const int* __restrict__ idx, u8* __restrict__ mo){
    const int v = blockIdx.x * 256 + threadIdx.x;
    const int xo = v & 63, yo = (v >> 6) & 63, zo = v >> 12;
    u8 a = 0;
    for (int kz = 0; kz < 3; ++kz){ int iz = 2*zo + kz - 1; if ((unsigned)iz >= 128u) continue;
      for (int ky = 0; ky < 3; ++ky){ int iy = 2*yo + ky - 1; if ((unsigned)iy >= 128u) continue;
        for (int kx = 0; kx < 3; ++kx){ int ix = 2*xo + kx - 1; if ((unsigned)ix >= 128u) continue;
          a |= (idx[((size_t)iz * 128 + iy) * 128 + ix] >= 0) ? 1 : 0;
    }}}
    mo[v] = a;
}

template<int DO>
__global__ __launch_bounds__(256)
void maskdown_k(const u8* __restrict__ mi, u8* __restrict__ mo){
    constexpr int DI = DO * 2;
    constexpr int LOG = ilog2c(DO);
    const int v = blockIdx.x * 256 + threadIdx.x;
    const int xo = v & (DO - 1), yo = (v >> LOG) & (DO - 1), zo = v >> (2 * LOG);
    u8 a = 0;
    for (int kz = 0; kz < 3; ++kz){ int iz = 2*zo + kz - 1; if ((unsigned)iz >= (unsigned)DI) continue;
      for (int ky = 0; ky < 3; ++ky){ int iy = 2*yo + ky - 1; if ((unsigned)iy >= (unsigned)DI) continue;
        for (int kx = 0; kx < 3; ++kx){ int ix = 2*xo + kx - 1; if ((unsigned)ix >= (unsigned)DI) continue;
          a |= mi[((size_t)iz * DI + iy) * DI + ix];
    }}}
    mo[v] = a;
}

// ---- MFMA sparse subm conv at 128^3: compact bf16 16ch -> 16ch ----
__global__ __launch_bounds__(256)
void sconvm_k(const u16* __restrict__ fin, const int* __restrict__ idxmap,
              const int* __restrict__ alist, const u32* __restrict__ cnt,
              const u16* __restrict__ wf, const float* __restrict__ sc,
              const float* __restrict__ sh, u16* __restrict__ fout){
    const int n = min((int)cnt[0], CAP);
    const int j = blockIdx.x * 4 + (threadIdx.x >> 6);
    const int sbase = j * 16;
    if (sbase >= n) return;
    const int lane = threadIdx.x & 63;
    const int m = lane & 15, quad = lane >> 4;

    const int s = sbase + m;
    const int v = (s < n) ? alist[s] : -1;
    int xo = 0, yo = 0, zo = 0;
    if (v >= 0){ xo = v & 127; yo = (v >> 7) & 127; zo = v >> 14; }

    f32x4 acc = {0.f,0.f,0.f,0.f};
    for (int p = 0; p < 14; ++p){
        const int tp = p * 2 + (quad >> 1);
        short8 a = {0,0,0,0,0,0,0,0};
        if (v >= 0 && tp < 27){
            const int kz = tp / 9, ky = (tp / 3) % 3, kx = tp % 3;
            const int iz = zo + kz - 1, iy = yo + ky - 1, ix = xo + kx - 1;
            if ((unsigned)iz < 128u && (unsigned)iy < 128u && (unsigned)ix < 128u){
                const int sn = idxmap[((size_t)iz * 128 + iy) * 128 + ix];
                if (sn >= 0) a = *(const short8*)(fin + (size_t)sn * 16 + (quad & 1) * 8);
            }
        }
        short8 b = *(const short8*)(wf + ((size_t)p * 64 + lane) * 8);
        acc = __builtin_amdgcn_mfma_f32_16x16x32_bf16(a, b, acc, 0, 0, 0);
    }

    const int co = lane & 15;
    const float scl = sc[co], shf = sh[co];
    #pragma unroll
    for (int r = 0; r < 4; ++r){
        const int srow = sbase + quad * 4 + r;
        if (srow < n){
            fout[(size_t)srow * 16 + co] = f2bf(fmaxf(acc[r] * scl + shf, 0.f));
        }
    }
}

// ---- down0 MFMA: compact bf16 16ch @128^3 (idxmap gather) -> bf16 NDHWC 32ch @64^3 ----
__global__ __launch_bounds__(256)
void convd0m_k(const u16* __restrict__ fbuf, const int* __restrict__ idxmap,
               const u16* __restrict__ wf, const float* __restrict__ sc,
               const float* __restrict__ sh, const u8* __restrict__ mk,
               u16* __restrict__ out)
{
    const int wj = blockIdx.x * 4 + (threadIdx.x >> 6);
    const int lane = threadIdx.x & 63;
    const int m = lane & 15, quad = lane >> 4;
    const int xo_b = (wj & 3) * 16;
    const int yo = (wj >> 2) & 63;
    const int zo = wj >> 8;

    f32x4 acc0 = {0.f,0.f,0.f,0.f}, acc1 = {0.f,0.f,0.f,0.f};
    const int ix_m = (xo_b + m) * 2 - 1;

    for (int p = 0; p < 14; ++p){
        const int tp = p * 2 + (quad >> 1);
        short8 a = {0,0,0,0,0,0,0,0};
        if (tp < 27){
            const int kz = tp / 9, ky = (tp / 3) % 3, kx = tp % 3;
            const int iz = 2*zo + kz - 1, iy = 2*yo + ky - 1, ix = ix_m + kx;
            if ((unsigned)iz < 128u && (unsigned)iy < 128u && (unsigned)ix < 128u){
                const int sn = idxmap[((size_t)iz * 128 + iy) * 128 + ix];
                if (sn >= 0) a = *(const short8*)(fbuf + (size_t)sn * 16 + (quad & 1) * 8);
            }
        }
        short8 b0 = *(const short8*)(wf + ((size_t)(p*2+0) * 64 + lane) * 8);
        short8 b1 = *(const short8*)(wf + ((size_t)(p*2+1) * 64 + lane) * 8);
        acc0 = __builtin_amdgcn_mfma_f32_16x16x32_bf16(a, b0, acc0, 0, 0, 0);
        acc1 = __builtin_amdgcn_mfma_f32_16x16x32_bf16(a, b1, acc1, 0, 0, 0);
    }

    const int vb = wj * 16 + quad * 4;
    const u32 m4 = *(const u32*)(mk + vb);
    const int n = lane & 15;
    #pragma unroll
    for (int nt = 0; nt < 2; ++nt){
        const int co = nt * 16 + n;
        const float s = sc[co], h = sh[co];
        const f32x4 acc = nt ? acc1 : acc0;
        #pragma unroll
        for (int r = 0; r < 4; ++r){
            float val = fmaxf(acc[r] * s + h, 0.f);
            val = ((m4 >> (8*r)) & 0xFFu) ? val : 0.f;
            out[(size_t)(vb + r) * 32 + co] = f2bf(val);
        }
    }
}

// ---- generic direct-global MFMA conv; retained for down1 (stride 2) only ----
template<int DIN, int DOUT, int CIN, int COUT, int STRIDE, bool FINAL>
__global__ __launch_bounds__(256)
void mconv_k(const u16* __restrict__ in, const u16* __restrict__ wf,
             const float* __restrict__ sc, const float* __restrict__ sh,
             const u8* __restrict__ mk, void* __restrict__ out,
             const u32* __restrict__ flag)
{
    constexpr int KC = CIN / 32;
    constexpr int NT = COUT / 16;
    constexpr int XT = DOUT / 16;
    const int wj = blockIdx.x * 4 + (threadIdx.x >> 6);
    const int lane = threadIdx.x & 63;
    const int m = lane & 15, quad = lane >> 4;

    const int xo_b = (wj % XT) * 16;
    const int yo = (wj / XT) % DOUT;
    const int zo = wj / (XT * DOUT);

    f32x4 acc[NT];
    #pragma unroll
    for (int i = 0; i < NT; ++i) acc[i] = (f32x4){0.f,0.f,0.f,0.f};

    const int ix0 = (xo_b + m) * STRIDE - 1;
    for (int kz = 0; kz < 3; ++kz){
      const int iz = zo * STRIDE + kz - 1;
      if ((unsigned)iz >= (unsigned)DIN) continue;
      for (int ky = 0; ky < 3; ++ky){
        const int iy = yo * STRIDE + ky - 1;
        if ((unsigned)iy >= (unsigned)DIN) continue;
        const size_t rowb = ((size_t)iz * DIN + iy) * DIN;
        #pragma unroll
        for (int kx = 0; kx < 3; ++kx){
          const int ix = ix0 + kx;
          const bool v = (unsigned)ix < (unsigned)DIN;
          const int tap = (kz*3 + ky)*3 + kx;
          const u16* ap = in + (rowb + ix) * CIN + quad * 8;
          const u16* bp = wf + (size_t)tap * KC * NT * 512 + lane * 8;
          #pragma unroll
          for (int kc = 0; kc < KC; ++kc){
            short8 a = {0,0,0,0,0,0,0,0};
            if (v) a = *(const short8*)(ap + kc * 32);
            #pragma unroll
            for (int nt = 0; nt < NT; ++nt){
              short8 b = *(const short8*)(bp + (kc * NT + nt) * 512);
              acc[nt] = __builtin_amdgcn_mfma_f32_16x16x32_bf16(a, b, acc[nt], 0, 0, 0);
            }
          }
    }}}

    const int vb = wj * 16 + quad * 4;
    const u32 m4 = *(const u32*)(mk + vb);
    const int n = lane & 15;
    #pragma unroll
    for (int nt = 0; nt < NT; ++nt){
        const int co = nt * 16 + n;
        const float s = sc[co], h = sh[co];
        #pragma unroll
        for (int r = 0; r < 4; ++r){
            float val = fmaxf(acc[nt][r] * s + h, 0.f);
            val = ((m4 >> (8*r)) & 0xFFu) ? val : 0.f;
            ((u16*)out)[(size_t)(vb + r) * COUT + co] = f2bf(val);
        }
    }
    (void)flag;
}

// ---- LDS-staged MFMA conv, stride 1: block covers full x-row at one (yo,zo) ----
// LDS tile transposed to [c8][x][8ch] per row -> contiguous conflict-free ds_read_b128.
template<int D, int CIN, int COUT, int WAVES, bool FINAL>
__global__ __launch_bounds__(WAVES*64)
void mconvlds_k(const u16* __restrict__ in, const u16* __restrict__ wf,
                const float* __restrict__ sc, const float* __restrict__ sh,
                const u8* __restrict__ mk, void* __restrict__ out,
                const u32* __restrict__ flag)
{
    constexpr int KC = CIN / 32;
    constexpr int NT = COUT / 16;
    constexpr int CH8 = CIN / 8;
    constexpr int BT = WAVES * 64;
    __shared__ u16 tile[9 * 2048];     // 9 rows x D*CIN u16 (D*CIN==2048 both shapes)

    const int t = threadIdx.x;
    const int yo = blockIdx.x % D, zo = blockIdx.x / D;

    // stage up to 9 rows, transposing [x][ch] -> [c8][x][8]
    for (int dz = 0; dz < 3; ++dz){
      const int iz = zo + dz - 1;
      for (int dy = 0; dy < 3; ++dy){
        const int iy = yo + dy - 1;
        if ((unsigned)iz < (unsigned)D && (unsigned)iy < (unsigned)D){
          const u16* src = in + ((size_t)(iz * D + iy) * D) * CIN;
          u16* dst = &tile[(dz * 3 + dy) * 2048];
          for (int c = t; c < D * CH8; c += BT){
            const int x = c / CH8, c8 = c % CH8;
            *(short8*)(dst + (c8 * D + x) * 8) = *(const short8*)(src + c * 8);
          }
        }
      }
    }
    __syncthreads();

    const int lane = t & 63, w = t >> 6;
    const int m = lane & 15, quad = lane >> 4;
    const int xo_b = w * 16;

    f32x4 acc[NT];
    #pragma unroll
    for (int i = 0; i < NT; ++i) acc[i] = (f32x4){0.f,0.f,0.f,0.f};

    #pragma unroll
    for (int kz = 0; kz < 3; ++kz){
      const int iz = zo + kz - 1;
      if ((unsigned)iz >= (unsigned)D) continue;
      #pragma unroll
      for (int ky = 0; ky < 3; ++ky){
        const int iy = yo + ky - 1;
        if ((unsigned)iy >= (unsigned)D) continue;
        const u16* row = &tile[(kz * 3 + ky) * 2048];
        #pragma unroll
        for (int kx = 0; kx < 3; ++kx){
          const int ix = xo_b + m + kx - 1;
          const bool aok = (unsigned)ix < (unsigned)D;
          const int tap = (kz * 3 + ky) * 3 + kx;
          const u16* bp = wf + (size_t)tap * KC * NT * 512 + lane * 8;
          #pragma unroll
          for (int kc = 0; kc < KC; ++kc){
            short8 a = {0,0,0,0,0,0,0,0};
            if (aok) a = *(const short8*)(row + ((kc * 4 + quad) * D + ix) * 8);
            #pragma unroll
            for (int nt = 0; nt < NT; ++nt){
              short8 b = *(const short8*)(bp + (kc * NT + nt) * 512);
              acc[nt] = __builtin_amdgcn_mfma_f32_16x16x32_bf16(a, b, acc[nt], 0, 0, 0);
            }
          }
        }
      }
    }

    const int vb = (zo * D + yo) * D + xo_b + quad * 4;
    const u32 m4 = *(const u32*)(mk + vb);
    const int n = lane & 15;
    if (FINAL) {
        const bool bfout = flag[0] != 0;
        #pragma unroll
        for (int nt = 0; nt < NT; ++nt){
            const int co = nt * 16 + n;
            const float s = sc[co], h = sh[co];
            float4 o;
            float* po = &o.x;
            #pragma unroll
            for (int r = 0; r < 4; ++r){
                float val = fmaxf(acc[nt][r] * s + h, 0.f);
                po[r] = ((m4 >> (8*r)) & 0xFFu) ? val : 0.f;
            }
            if (!bfout) {
                *(float4*)((float*)out + (size_t)co * (D*D*D) + vb) = o;
            } else {
                u16* ob = (u16*)out + (size_t)co * (D*D*D) + vb;
                #pragma unroll
                for (int r = 0; r < 4; ++r) ob[r] = f2bf(po[r]);
            }
        }
    } else {
        #pragma unroll
        for (int nt = 0; nt < NT; ++nt){
            const int co = nt * 16 + n;
            const float s = sc[co], h = sh[co];
            #pragma unroll
            for (int r = 0; r < 4; ++r){
                float val = fmaxf(acc[nt][r] * s + h, 0.f);
                val = ((m4 >> (8*r)) & 0xFFu) ? val : 0.f;
                ((u16*)out)[(size_t)(vb + r) * COUT + co] = f2bf(val);
            }
        }
    }
}

extern "C" void kernel_launch(void* const* d_in, const int* in_sizes, int n_in,
                              void* d_out, int out_size, void* d_ws, size_t ws_size,
                              hipStream_t stream)
{
    (void)out_size; (void)ws_size;

    int wb = 2;
    for (int i = 1; i < n_in; ++i) { if (in_sizes[i] == 6912) { wb = i; break; } }

    const void* x = d_in[0];
    const void *w0a=d_in[wb+0],  *s0a=d_in[wb+1],  *b0a=d_in[wb+2];
    const void *w0b=d_in[wb+3],  *s0b=d_in[wb+4],  *b0b=d_in[wb+5];
    const void *wd0=d_in[wb+6],  *sd0=d_in[wb+7],  *bd0=d_in[wb+8];
    const void *w1a=d_in[wb+9],  *s1a=d_in[wb+10], *b1a=d_in[wb+11];
    const void *w1b=d_in[wb+12], *s1b=d_in[wb+13], *b1b=d_in[wb+14];
    const void *wd1=d_in[wb+15], *sd1=d_in[wb+16], *bd1=d_in[wb+17];
    const void *w2a=d_in[wb+18], *s2a=d_in[wb+19], *b2a=d_in[wb+20];
    const void *w2b=d_in[wb+21], *s2b=d_in[wb+22], *b2b=d_in[wb+23];
    const void *w2c=d_in[wb+24], *s2c=d_in[wb+25], *b2c=d_in[wb+26];

    // ---- workspace layout (~58 MiB) ----
    char* ws = (char*)d_ws;
    int*   idxmap = (int*)(ws);                     //  8,388,608
    u16*   Fb0    = (u16*)(ws + 8388608);           //  4,194,304
    u16*   Fb1    = (u16*)(ws + 12582912);          //  4,194,304
    u16*   Fb2    = (u16*)(ws + 16777216);          //  4,194,304
    u16*   Rb1    = (u16*)(ws + 25165824);          // 16,777,216
    u16*   Rb2    = (u16*)(ws + 41943040);          // 16,777,216
    u8*    m1     = (u8*)(ws + 58720256);           //    262,144
    u8*    m2     = (u8*)(ws + 58982400);           //     32,768
    u32*   cnt    = (u32*)(ws + 59015168);          //        256
    int*   alist  = (int*)(ws + 59015424);          //    524,288
    u16*   FR     = (u16*)(ws + 59539712);          //    942,080 (fragment arena)
    float* S      = (float*)(ws + 60481792);        //      3,072
    u32*   flag   = (u32*)(ws + 60484864);          //         64
    u64*   bmask  = (u64*)(ws + 60485120);          //    262,144
    u32*   bcnt   = (u32*)(ws + 60747264);          //     32,768
    u32*   boff   = (u32*)(ws + 60780032);          //     32,768

    // fragment arena offsets (u16 elements)
    u16* wfs0a = FR + 0;        //   7,168
    u16* wfs0b = FR + 7168;     //   7,168
    u16* fd0   = FR + 14336;    //  14,336
    u16* f1a   = FR + 28672;    //  27,648
    u16* f1b   = FR + 56320;    //  27,648
    u16* fd1   = FR + 83968;    //  55,296
    u16* f2a   = FR + 139264;   // 110,592
    u16* f2b   = FR + 249856;   // 110,592
    u16* f2c   = FR + 360448;   // 110,592  -> total 471,040

    detect_k<<<1, 64, 0, stream>>>((const u16*)s0a, flag);

    PJobs J;
    const void* jsrc[9] = {w0a, w0b, wd0, w1a, w1b, wd1, w2a, w2b, w2c};
    const u32 jlen[9]   = {7168,7168,14336,27648,27648,55296,110592,110592,110592};
    const int jcin[9]   = {16,16,16,32,32,32,64,64,64};
    const int jcout[9]  = {16,16,32,32,32,64,64,64,64};
    const int jmode[9]  = {2,2,1,0,0,0,0,0,0};
    u32 acc = 0;
    for (int i = 0; i < 9; ++i){
        J.src[i] = jsrc[i]; J.start[i] = acc; acc += jlen[i];
        J.cin[i] = jcin[i]; J.cout[i] = jcout[i]; J.mode[i] = jmode[i];
    }
    J.start[9] = acc;   // 471,040
    prep_k<<<(int)((acc + 255) / 256), 256, 0, stream>>>(J, FR, flag);

    P18 ps;
    const void* sv[18] = {s0a,b0a,s0b,b0b,sd0,bd0,s1a,b1a,s1b,b1b,sd1,bd1,s2a,b2a,s2b,b2b,s2c,b2c};
    for (int i = 0; i < 18; ++i) ps.p[i] = sv[i];
    scales_k<<<18, 64, 0, stream>>>(ps, S, flag);
    float *cs0a=S+0,  *cb0a=S+16,  *cs0b=S+32,  *cb0b=S+48;
    float *csd0=S+64, *cbd0=S+96,  *cs1a=S+128, *cb1a=S+160, *cs1b=S+192, *cb1b=S+224;
    float *csd1=S+256,*cbd1=S+320, *cs2a=S+384, *cb2a=S+448, *cs2b=S+512, *cb2b=S+576, *cs2c=S+640, *cb2c=S+704;

    // deterministic compaction (atomic-free)
    actmask_k<<<8192, 256, 0, stream>>>(x, bmask, bcnt, flag);
    scan_k<<<1, 1024, 0, stream>>>(bcnt, boff, cnt);
    scatter_k<<<8192, 256, 0, stream>>>(bmask, boff, idxmap, alist);
    m1_k<<<1024, 256, 0, stream>>>(idxmap, m1);
    maskdown_k<32><<<128, 256, 0, stream>>>(m1, m2);

    // stage A (128^3, 16ch, ~5% active) — compact bf16 MFMA
    gatherb_k<<<8192, 256, 0, stream>>>(x, alist, cnt, Fb0, flag);
    sconvm_k<<<2048, 256, 0, stream>>>(Fb0, idxmap, alist, cnt, wfs0a, cs0a, cb0a, Fb1);
    sconvm_k<<<2048, 256, 0, stream>>>(Fb1, idxmap, alist, cnt, wfs0b, cs0b, cb0b, Fb2);
    // down0 MFMA -> 64^3 x 32 bf16 NDHWC
    convd0m_k<<<4096, 256, 0, stream>>>(Fb2, idxmap, fd0, csd0, cbd0, m1, Rb1);
    // 64^3 stage — LDS-staged
    mconvlds_k<64,32,32,4,false><<<4096, 256, 0, stream>>>(Rb1, f1a, cs1a, cb1a, m1, Rb2, flag);
    mconvlds_k<64,32,32,4,false><<<4096, 256, 0, stream>>>(Rb2, f1b, cs1b, cb1b, m1, Rb1, flag);
    // down1 -> 32^3 x 64 (stride 2, direct-global path)
    mconv_k<64,32,32,64,2,false><<<512, 256, 0, stream>>>(Rb1, fd1, csd1, cbd1, m2, Rb2, flag);
    // 32^3 stage — LDS-staged
    mconvlds_k<32,64,64,2,false><<<1024, 128, 0, stream>>>(Rb2, f2a, cs2a, cb2a, m2, Rb1, flag);
    mconvlds_k<32,64,64,2,false><<<1024, 128, 0, stream>>>(Rb1, f2b, cs2b, cb2b, m2, Rb2, flag);
    // final conv: NCDHW f32 (or bf16 per flag) to d_out
    mconvlds_k<32,64,64,2,true ><<<1024, 128, 0, stream>>>(Rb2, f2c, cs2c, cb2c, m2, d_out, flag);
}